// Round 7
// baseline (352.972 us; speedup 1.0000x reference)
//
#include <hip/hip_runtime.h>
#include <cstddef>
#include <cstdint>

typedef float f4 __attribute__((ext_vector_type(4)));
typedef unsigned long long u64;
typedef unsigned short u16;
typedef unsigned char u8;
typedef unsigned short u16x8 __attribute__((ext_vector_type(8)));
typedef short short8 __attribute__((ext_vector_type(8)));

__device__ __forceinline__ u64 ldnt8(const void* p) {
    return __builtin_nontemporal_load((const u64*)(p));
}
// bf16 round-to-nearest-even
__device__ __forceinline__ u16 bfrn(float f) {
    unsigned u = __float_as_uint(f);
    return (u16)((u + 0x7FFFu + ((u >> 16) & 1u)) >> 16);
}
__device__ __forceinline__ float bl(unsigned w) { return __uint_as_float(w << 16); }
__device__ __forceinline__ float bh(unsigned w) { return __uint_as_float(w & 0xFFFF0000u); }

// ---------------------------------------------------------------------------
// GraphConv x3 (DGL norm='both', per-edge weight)
//   coef[e] = ew[e] * out_norm[src[e]]  (fused into CSR)
// CSR build: two-level counting sort (LDS atomics only).
// Layers 0/1: fused gather-aggregate + MFMA GEMM (k_aggemm).
// ---------------------------------------------------------------------------

#define EPB 4096

__global__ void __launch_bounds__(256)
k_p1(const int* __restrict__ src, const int* __restrict__ dst,
     u16* __restrict__ lrank_s, u16* __restrict__ lrank_d,
     int* __restrict__ bh_s, int* __restrict__ bh_d, int NB, int E) {
    __shared__ int hs[512], hd[512];
    const int t = threadIdx.x, b = blockIdx.x;
    for (int i = t; i < NB; i += 256) { hs[i] = 0; hd[i] = 0; }
    __syncthreads();
    const int e0 = b * EPB;
    #pragma unroll
    for (int j = 0; j < 4; ++j) {
        const int e = e0 + j * 1024 + t * 4;
        if (e + 4 <= E) {
            const int4 d = *(const int4*)&dst[e];
            const int4 s = *(const int4*)&src[e];
            unsigned rd0 = atomicAdd(&hd[d.x >> 8], 1);
            unsigned rd1 = atomicAdd(&hd[d.y >> 8], 1);
            unsigned rd2 = atomicAdd(&hd[d.z >> 8], 1);
            unsigned rd3 = atomicAdd(&hd[d.w >> 8], 1);
            unsigned rs0 = atomicAdd(&hs[s.x >> 8], 1);
            unsigned rs1 = atomicAdd(&hs[s.y >> 8], 1);
            unsigned rs2 = atomicAdd(&hs[s.z >> 8], 1);
            unsigned rs3 = atomicAdd(&hs[s.w >> 8], 1);
            *(uint2*)&lrank_d[e] = make_uint2(rd0 | (rd1 << 16), rd2 | (rd3 << 16));
            *(uint2*)&lrank_s[e] = make_uint2(rs0 | (rs1 << 16), rs2 | (rs3 << 16));
        } else {
            for (int k = e; k < E && k < e + 4; ++k) {
                lrank_d[k] = (u16)atomicAdd(&hd[dst[k] >> 8], 1);
                lrank_s[k] = (u16)atomicAdd(&hs[src[k] >> 8], 1);
            }
        }
    }
    __syncthreads();
    for (int i = t; i < NB; i += 256) {
        bh_d[b * NB + i] = hd[i];
        bh_s[b * NB + i] = hs[i];
    }
}

__global__ void __launch_bounds__(512)
k_p2(int* __restrict__ bh_d, int* __restrict__ bh_s,
     int* __restrict__ cb_d, int* __restrict__ cb_s, int NB, int B1) {
    __shared__ int s[512];
    const int B = blockIdx.x, i = threadIdx.x;
    int* bh = blockIdx.y ? bh_s : bh_d;
    int* cb = blockIdx.y ? cb_s : cb_d;
    const int v = (i < B1) ? bh[i * NB + B] : 0;
    s[i] = v;
    __syncthreads();
    for (int off = 1; off < 512; off <<= 1) {
        const int x = (i >= off) ? s[i - off] : 0;
        __syncthreads();
        s[i] += x;
        __syncthreads();
    }
    if (i < B1) bh[i * NB + B] = s[i] - v;
    if (i == 511) cb[B] = s[511];
}

__global__ void __launch_bounds__(512)
k_p2b(const int* __restrict__ cb_d, const int* __restrict__ cb_s,
      int* __restrict__ bktb_d, int* __restrict__ bktb_s,
      int* __restrict__ row, int NB, int N, int E) {
    __shared__ int s[512];
    const int t = threadIdx.x;
    int v = (t < NB) ? cb_d[t] : 0;
    s[t] = v;
    __syncthreads();
    for (int off = 1; off < 512; off <<= 1) {
        const int x = (t >= off) ? s[t - off] : 0;
        __syncthreads();
        s[t] += x;
        __syncthreads();
    }
    if (t < NB) bktb_d[t] = s[t] - v;
    __syncthreads();
    v = (t < NB) ? cb_s[t] : 0;
    s[t] = v;
    __syncthreads();
    for (int off = 1; off < 512; off <<= 1) {
        const int x = (t >= off) ? s[t - off] : 0;
        __syncthreads();
        s[t] += x;
        __syncthreads();
    }
    if (t < NB) bktb_s[t] = s[t] - v;
    if (t == 0) row[N] = E;
}

__global__ void __launch_bounds__(256)
k_p3(const int* __restrict__ src, const int* __restrict__ dst,
     const float* __restrict__ ew,
     const u16* __restrict__ lrank_s, const u16* __restrict__ lrank_d,
     const int* __restrict__ bh_s, const int* __restrict__ bh_d,
     const int* __restrict__ bktb_s, const int* __restrict__ bktb_d,
     u8* __restrict__ tdst, int2* __restrict__ tsw, u8* __restrict__ tsrc,
     int NB, int E) {
    const int t = threadIdx.x, b = blockIdx.x;
    const int e0 = b * EPB;
    #pragma unroll
    for (int j = 0; j < 4; ++j) {
        const int e = e0 + j * 1024 + t * 4;
        if (e + 4 <= E) {
            const int4 d = *(const int4*)&dst[e];
            const int4 s = *(const int4*)&src[e];
            const f4   w = *(const f4*)&ew[e];
            const uint2 rd = *(const uint2*)&lrank_d[e];
            const uint2 rs = *(const uint2*)&lrank_s[e];
            const int dd[4] = {d.x, d.y, d.z, d.w};
            const int ss[4] = {s.x, s.y, s.z, s.w};
            const float ww[4] = {w.x, w.y, w.z, w.w};
            const int rrd[4] = {(int)(rd.x & 0xFFFF), (int)(rd.x >> 16),
                                (int)(rd.y & 0xFFFF), (int)(rd.y >> 16)};
            const int rrs[4] = {(int)(rs.x & 0xFFFF), (int)(rs.x >> 16),
                                (int)(rs.y & 0xFFFF), (int)(rs.y >> 16)};
            #pragma unroll
            for (int k = 0; k < 4; ++k) {
                const int Bd = dd[k] >> 8;
                const int posd = bktb_d[Bd] + bh_d[b * NB + Bd] + rrd[k];
                tdst[posd] = (u8)(dd[k] & 255);
                tsw[posd] = make_int2(ss[k], __float_as_int(ww[k]));
                const int Bs = ss[k] >> 8;
                const int poss = bktb_s[Bs] + bh_s[b * NB + Bs] + rrs[k];
                tsrc[poss] = (u8)(ss[k] & 255);
            }
        } else {
            for (int k = e; k < E && k < e + 4; ++k) {
                const int dv = dst[k], sv = src[k];
                const int Bd = dv >> 8;
                const int posd = bktb_d[Bd] + bh_d[b * NB + Bd] + (int)lrank_d[k];
                tdst[posd] = (u8)(dv & 255);
                tsw[posd] = make_int2(sv, __float_as_int(ew[k]));
                const int Bs = sv >> 8;
                const int poss = bktb_s[Bs] + bh_s[b * NB + Bs] + (int)lrank_s[k];
                tsrc[poss] = (u8)(sv & 255);
            }
        }
    }
}

__global__ void __launch_bounds__(256)
k_p4s(const u8* __restrict__ tsrc, const int* __restrict__ bktb_s,
      const int* __restrict__ cb_s, float* __restrict__ onorm, int NB, int N) {
    __shared__ int cnt[256];
    const int B = blockIdx.x, t = threadIdx.x;
    cnt[t] = 0;
    __syncthreads();
    const int base = bktb_s[B], cb = cb_s[B];
    for (int i = t; i < cb; i += 256) atomicAdd(&cnt[tsrc[base + i]], 1);
    __syncthreads();
    const int n = (B << 8) + t;
    if (n < N) {
        const int c = cnt[t];
        onorm[n] = rsqrtf((float)(c < 1 ? 1 : c));
    }
}

__global__ void __launch_bounds__(256)
k_p4d(const u8* __restrict__ tdst, const int2* __restrict__ tsw,
      const int* __restrict__ bktb_d, const int* __restrict__ cb_d,
      const float* __restrict__ onorm, int* __restrict__ row,
      float* __restrict__ inorm, int2* __restrict__ csr, int NB, int N) {
    __shared__ int cnt[256], cnt2[256], lrow[256], sc[256];
    const int B = blockIdx.x, t = threadIdx.x;
    cnt[t] = 0; cnt2[t] = 0;
    __syncthreads();
    const int base = bktb_d[B], cb = cb_d[B];
    for (int i = t; i < cb; i += 256) atomicAdd(&cnt[tdst[base + i]], 1);
    __syncthreads();
    const int v = cnt[t];
    sc[t] = v;
    __syncthreads();
    for (int off = 1; off < 256; off <<= 1) {
        const int x = (t >= off) ? sc[t - off] : 0;
        __syncthreads();
        sc[t] += x;
        __syncthreads();
    }
    const int excl = sc[t] - v;
    lrow[t] = excl;
    const int n = (B << 8) + t;
    if (n < N) {
        row[n] = base + excl;
        inorm[n] = rsqrtf((float)(v < 1 ? 1 : v));
    }
    __syncthreads();
    for (int i = t; i < cb; i += 256) {
        const int d = tdst[base + i];
        const int2 sw = tsw[base + i];
        const int r = atomicAdd(&cnt2[d], 1);
        const float coef = __int_as_float(sw.y) * onorm[sw.x];
        csr[base + lrow[d] + r] = make_int2(sw.x, __float_as_int(coef));
    }
}

// fp32 -> bf16 conversion, 8 elems/thread
__global__ void __launch_bounds__(256)
k_cvt(const float* __restrict__ in, u16* __restrict__ out, int n8) {
    const int i = blockIdx.x * blockDim.x + threadIdx.x;
    if (i < n8) {
        const f4 v0 = *(const f4*)(in + (size_t)i * 8);
        const f4 v1 = *(const f4*)(in + (size_t)i * 8 + 4);
        u16x8 r = {bfrn(v0.x), bfrn(v0.y), bfrn(v0.z), bfrn(v0.w),
                   bfrn(v1.x), bfrn(v1.y), bfrn(v1.z), bfrn(v1.w)};
        *(u16x8*)(out + (size_t)i * 8) = r;
    }
}

// all three W -> Wt (transposed bf16) in one launch
__global__ void __launch_bounds__(256)
k_wcvt3(const float* __restrict__ W0, const float* __restrict__ W1,
        const float* __restrict__ W2, u16* __restrict__ Wt0,
        u16* __restrict__ Wt1, u16* __restrict__ Wt2) {
    const int i = blockIdx.x * 256 + threadIdx.x;
    if (i < 16384) {
        const int k = i >> 7, c = i & 127;
        Wt0[c * 128 + k] = bfrn(W0[i]);
    } else if (i < 32768) {
        const int j = i - 16384, k = j >> 7, c = j & 127;
        Wt1[c * 128 + k] = bfrn(W1[j]);
    } else if (i < 40960) {
        const int j = i - 32768, k = j >> 6, c = j & 63;
        Wt2[c * 128 + k] = bfrn(W2[j]);
    }
}

// Fused layer: per block, 4 waves x 16 nodes. Each wave aggregates its 16
// nodes (quarter-wave per edge) into a 16x128 bf16 LDS tile, then (intra-wave,
// no barrier) consumes the tile as MFMA A-fragments against global Wt.
// C = relu(agg @ W + b) in bf16.
template <bool RELU>
__global__ void __launch_bounds__(256, 8)
k_aggemm(const u16* __restrict__ h, const int* __restrict__ row,
         const int2* __restrict__ csr, const float* __restrict__ inorm,
         const u16* __restrict__ Wt, const float* __restrict__ bias,
         u16* __restrict__ C, int N) {
    __shared__ u16 Yt[64][136];
    const int t = threadIdx.x, lane = t & 63, wave = t >> 6;
    const int q = lane >> 4, col = (lane & 15) * 8;
    const int nbase = blockIdx.x * 64 + wave * 16;

    int rv = 0;
    if (lane <= 16) rv = row[min(nbase + lane, N)];

    for (int i = 0; i < 16; ++i) {
        const int node = nbase + i;
        if (node >= N) break;
        int p = __shfl(rv, i);
        const int e = __shfl(rv, i + 1);
        float a0 = 0, a1 = 0, a2 = 0, a3 = 0, a4 = 0, a5 = 0, a6 = 0, a7 = 0;
        for (; p + 16 <= e; p += 16) {
            const u64 c0 = ldnt8(&csr[p + q]);
            const u64 c1 = ldnt8(&csr[p + 4 + q]);
            const u64 c2 = ldnt8(&csr[p + 8 + q]);
            const u64 c3 = ldnt8(&csr[p + 12 + q]);
            const uint4 w0 = *(const uint4*)(h + (size_t)(int)c0 * 128 + col);
            const uint4 w1 = *(const uint4*)(h + (size_t)(int)c1 * 128 + col);
            const uint4 w2 = *(const uint4*)(h + (size_t)(int)c2 * 128 + col);
            const uint4 w3 = *(const uint4*)(h + (size_t)(int)c3 * 128 + col);
            const float f0 = __int_as_float((int)(c0 >> 32));
            const float f1 = __int_as_float((int)(c1 >> 32));
            const float f2 = __int_as_float((int)(c2 >> 32));
            const float f3 = __int_as_float((int)(c3 >> 32));
            a0 = fmaf(f0, bl(w0.x), a0); a1 = fmaf(f0, bh(w0.x), a1);
            a2 = fmaf(f0, bl(w0.y), a2); a3 = fmaf(f0, bh(w0.y), a3);
            a4 = fmaf(f0, bl(w0.z), a4); a5 = fmaf(f0, bh(w0.z), a5);
            a6 = fmaf(f0, bl(w0.w), a6); a7 = fmaf(f0, bh(w0.w), a7);
            a0 = fmaf(f1, bl(w1.x), a0); a1 = fmaf(f1, bh(w1.x), a1);
            a2 = fmaf(f1, bl(w1.y), a2); a3 = fmaf(f1, bh(w1.y), a3);
            a4 = fmaf(f1, bl(w1.z), a4); a5 = fmaf(f1, bh(w1.z), a5);
            a6 = fmaf(f1, bl(w1.w), a6); a7 = fmaf(f1, bh(w1.w), a7);
            a0 = fmaf(f2, bl(w2.x), a0); a1 = fmaf(f2, bh(w2.x), a1);
            a2 = fmaf(f2, bl(w2.y), a2); a3 = fmaf(f2, bh(w2.y), a3);
            a4 = fmaf(f2, bl(w2.z), a4); a5 = fmaf(f2, bh(w2.z), a5);
            a6 = fmaf(f2, bl(w2.w), a6); a7 = fmaf(f2, bh(w2.w), a7);
            a0 = fmaf(f3, bl(w3.x), a0); a1 = fmaf(f3, bh(w3.x), a1);
            a2 = fmaf(f3, bl(w3.y), a2); a3 = fmaf(f3, bh(w3.y), a3);
            a4 = fmaf(f3, bl(w3.z), a4); a5 = fmaf(f3, bh(w3.z), a5);
            a6 = fmaf(f3, bl(w3.w), a6); a7 = fmaf(f3, bh(w3.w), a7);
        }
        for (; p + 8 <= e; p += 8) {
            const u64 c0 = ldnt8(&csr[p + q]);
            const u64 c1 = ldnt8(&csr[p + 4 + q]);
            const uint4 w0 = *(const uint4*)(h + (size_t)(int)c0 * 128 + col);
            const uint4 w1 = *(const uint4*)(h + (size_t)(int)c1 * 128 + col);
            const float f0 = __int_as_float((int)(c0 >> 32));
            const float f1 = __int_as_float((int)(c1 >> 32));
            a0 = fmaf(f0, bl(w0.x), a0); a1 = fmaf(f0, bh(w0.x), a1);
            a2 = fmaf(f0, bl(w0.y), a2); a3 = fmaf(f0, bh(w0.y), a3);
            a4 = fmaf(f0, bl(w0.z), a4); a5 = fmaf(f0, bh(w0.z), a5);
            a6 = fmaf(f0, bl(w0.w), a6); a7 = fmaf(f0, bh(w0.w), a7);
            a0 = fmaf(f1, bl(w1.x), a0); a1 = fmaf(f1, bh(w1.x), a1);
            a2 = fmaf(f1, bl(w1.y), a2); a3 = fmaf(f1, bh(w1.y), a3);
            a4 = fmaf(f1, bl(w1.z), a4); a5 = fmaf(f1, bh(w1.z), a5);
            a6 = fmaf(f1, bl(w1.w), a6); a7 = fmaf(f1, bh(w1.w), a7);
        }
        {
            const int i0 = p + q, i1 = p + 4 + q;
            if (i0 < e) {
                const u64 c = ldnt8(&csr[i0]);
                const uint4 w = *(const uint4*)(h + (size_t)(int)c * 128 + col);
                const float f = __int_as_float((int)(c >> 32));
                a0 = fmaf(f, bl(w.x), a0); a1 = fmaf(f, bh(w.x), a1);
                a2 = fmaf(f, bl(w.y), a2); a3 = fmaf(f, bh(w.y), a3);
                a4 = fmaf(f, bl(w.z), a4); a5 = fmaf(f, bh(w.z), a5);
                a6 = fmaf(f, bl(w.w), a6); a7 = fmaf(f, bh(w.w), a7);
            }
            if (i1 < e) {
                const u64 c = ldnt8(&csr[i1]);
                const uint4 w = *(const uint4*)(h + (size_t)(int)c * 128 + col);
                const float f = __int_as_float((int)(c >> 32));
                a0 = fmaf(f, bl(w.x), a0); a1 = fmaf(f, bh(w.x), a1);
                a2 = fmaf(f, bl(w.y), a2); a3 = fmaf(f, bh(w.y), a3);
                a4 = fmaf(f, bl(w.z), a4); a5 = fmaf(f, bh(w.z), a5);
                a6 = fmaf(f, bl(w.w), a6); a7 = fmaf(f, bh(w.w), a7);
            }
        }
        a0 += __shfl_xor(a0, 16); a1 += __shfl_xor(a1, 16);
        a2 += __shfl_xor(a2, 16); a3 += __shfl_xor(a3, 16);
        a4 += __shfl_xor(a4, 16); a5 += __shfl_xor(a5, 16);
        a6 += __shfl_xor(a6, 16); a7 += __shfl_xor(a7, 16);
        a0 += __shfl_xor(a0, 32); a1 += __shfl_xor(a1, 32);
        a2 += __shfl_xor(a2, 32); a3 += __shfl_xor(a3, 32);
        a4 += __shfl_xor(a4, 32); a5 += __shfl_xor(a5, 32);
        a6 += __shfl_xor(a6, 32); a7 += __shfl_xor(a7, 32);
        if (lane < 16) {
            const float nn = inorm[node];
            u16x8 r = {bfrn(a0 * nn), bfrn(a1 * nn), bfrn(a2 * nn), bfrn(a3 * nn),
                       bfrn(a4 * nn), bfrn(a5 * nn), bfrn(a6 * nn), bfrn(a7 * nn)};
            *(u16x8*)&Yt[wave * 16 + i][col] = r;
        }
    }

    // phase 2: GEMM on this wave's own tile (no barrier needed)
    const int c16 = lane & 15;
    const int koff = q * 8;
    short8 a[4];
    #pragma unroll
    for (int kk = 0; kk < 4; ++kk)
        a[kk] = *(const short8*)&Yt[wave * 16 + c16][kk * 32 + koff];

    #pragma unroll
    for (int ct = 0; ct < 8; ++ct) {
        f4 acc = {0.f, 0.f, 0.f, 0.f};
        #pragma unroll
        for (int kk = 0; kk < 4; ++kk) {
            const short8 b = *(const short8*)(Wt + (size_t)(ct * 16 + c16) * 128 + kk * 32 + koff);
            acc = __builtin_amdgcn_mfma_f32_16x16x32_bf16(a[kk], b, acc, 0, 0, 0);
        }
        const float bb = bias[ct * 16 + c16];
        #pragma unroll
        for (int r = 0; r < 4; ++r) {
            const int gr = nbase + q * 4 + r;
            if (gr < N) {
                float v = acc[r] + bb;
                if (RELU) v = v > 0.f ? v : 0.f;
                C[(size_t)gr * 128 + ct * 16 + c16] = bfrn(v);
            }
        }
    }
}

// layer-2 GEMM: C[N x 64] = A[N x 128] @ W2, bf16 io, no LDS (W L2-hot)
__global__ void __launch_bounds__(256, 8)
k_mgemm64(const u16* __restrict__ A, const u16* __restrict__ Wt,
          u16* __restrict__ C, int N) {
    const int t = threadIdx.x, lane = t & 63, wave = t >> 6;
    const int q = lane >> 4, c16 = lane & 15, koff = q * 8;
    const int row0 = blockIdx.x * 64 + wave * 16;
    if (row0 >= N) return;
    const int arow = min(row0 + c16, N - 1);
    short8 a[4];
    #pragma unroll
    for (int kk = 0; kk < 4; ++kk)
        a[kk] = *(const short8*)(A + (size_t)arow * 128 + kk * 32 + koff);
    #pragma unroll
    for (int ct = 0; ct < 4; ++ct) {
        f4 acc = {0.f, 0.f, 0.f, 0.f};
        #pragma unroll
        for (int kk = 0; kk < 4; ++kk) {
            const short8 b = *(const short8*)(Wt + (size_t)(ct * 16 + c16) * 128 + kk * 32 + koff);
            acc = __builtin_amdgcn_mfma_f32_16x16x32_bf16(a[kk], b, acc, 0, 0, 0);
        }
        #pragma unroll
        for (int r = 0; r < 4; ++r) {
            const int gr = row0 + q * 4 + r;
            if (gr < N) C[(size_t)gr * 64 + ct * 16 + c16] = bfrn(acc[r]);
        }
    }
}

// one wave per node, width 64 bf16: eighth-wave per edge; fused bias; fp32 out
__global__ void __launch_bounds__(256)
k_agg64b(const u16* __restrict__ h, const int* __restrict__ row,
         const int2* __restrict__ csr, const float* __restrict__ inorm,
         const float* __restrict__ bias, float* __restrict__ out, int N) {
    const int node = (int)((blockIdx.x * blockDim.x + threadIdx.x) >> 6);
    if (node >= N) return;
    const int lane = threadIdx.x & 63;
    const int oc = lane >> 3;
    const int col = (lane & 7) * 8;
    int p = row[node];
    const int e = row[node + 1];
    float a0 = 0, a1 = 0, a2 = 0, a3 = 0, a4 = 0, a5 = 0, a6 = 0, a7 = 0;
    for (; p + 16 <= e; p += 16) {
        const u64 c0 = ldnt8(&csr[p + oc]);
        const u64 c1 = ldnt8(&csr[p + 8 + oc]);
        const uint4 w0 = *(const uint4*)(h + (size_t)(int)c0 * 64 + col);
        const uint4 w1 = *(const uint4*)(h + (size_t)(int)c1 * 64 + col);
        const float f0 = __int_as_float((int)(c0 >> 32));
        const float f1 = __int_as_float((int)(c1 >> 32));
        a0 = fmaf(f0, bl(w0.x), a0); a1 = fmaf(f0, bh(w0.x), a1);
        a2 = fmaf(f0, bl(w0.y), a2); a3 = fmaf(f0, bh(w0.y), a3);
        a4 = fmaf(f0, bl(w0.z), a4); a5 = fmaf(f0, bh(w0.z), a5);
        a6 = fmaf(f0, bl(w0.w), a6); a7 = fmaf(f0, bh(w0.w), a7);
        a0 = fmaf(f1, bl(w1.x), a0); a1 = fmaf(f1, bh(w1.x), a1);
        a2 = fmaf(f1, bl(w1.y), a2); a3 = fmaf(f1, bh(w1.y), a3);
        a4 = fmaf(f1, bl(w1.z), a4); a5 = fmaf(f1, bh(w1.z), a5);
        a6 = fmaf(f1, bl(w1.w), a6); a7 = fmaf(f1, bh(w1.w), a7);
    }
    {
        const int i0 = p + oc, i1 = p + 8 + oc;
        if (i0 < e) {
            const u64 c = ldnt8(&csr[i0]);
            const uint4 w = *(const uint4*)(h + (size_t)(int)c * 64 + col);
            const float f = __int_as_float((int)(c >> 32));
            a0 = fmaf(f, bl(w.x), a0); a1 = fmaf(f, bh(w.x), a1);
            a2 = fmaf(f, bl(w.y), a2); a3 = fmaf(f, bh(w.y), a3);
            a4 = fmaf(f, bl(w.z), a4); a5 = fmaf(f, bh(w.z), a5);
            a6 = fmaf(f, bl(w.w), a6); a7 = fmaf(f, bh(w.w), a7);
        }
        if (i1 < e) {
            const u64 c = ldnt8(&csr[i1]);
            const uint4 w = *(const uint4*)(h + (size_t)(int)c * 64 + col);
            const float f = __int_as_float((int)(c >> 32));
            a0 = fmaf(f, bl(w.x), a0); a1 = fmaf(f, bh(w.x), a1);
            a2 = fmaf(f, bl(w.y), a2); a3 = fmaf(f, bh(w.y), a3);
            a4 = fmaf(f, bl(w.z), a4); a5 = fmaf(f, bh(w.z), a5);
            a6 = fmaf(f, bl(w.w), a6); a7 = fmaf(f, bh(w.w), a7);
        }
    }
    a0 += __shfl_xor(a0, 8);  a1 += __shfl_xor(a1, 8);
    a2 += __shfl_xor(a2, 8);  a3 += __shfl_xor(a3, 8);
    a4 += __shfl_xor(a4, 8);  a5 += __shfl_xor(a5, 8);
    a6 += __shfl_xor(a6, 8);  a7 += __shfl_xor(a7, 8);
    a0 += __shfl_xor(a0, 16); a1 += __shfl_xor(a1, 16);
    a2 += __shfl_xor(a2, 16); a3 += __shfl_xor(a3, 16);
    a4 += __shfl_xor(a4, 16); a5 += __shfl_xor(a5, 16);
    a6 += __shfl_xor(a6, 16); a7 += __shfl_xor(a7, 16);
    a0 += __shfl_xor(a0, 32); a1 += __shfl_xor(a1, 32);
    a2 += __shfl_xor(a2, 32); a3 += __shfl_xor(a3, 32);
    a4 += __shfl_xor(a4, 32); a5 += __shfl_xor(a5, 32);
    a6 += __shfl_xor(a6, 32); a7 += __shfl_xor(a7, 32);
    if (lane < 8) {
        const float nn = inorm[node];
        const f4 b0 = *(const f4*)(bias + col);
        const f4 b1 = *(const f4*)(bias + col + 4);
        f4 r0 = {a0 * nn + b0.x, a1 * nn + b0.y, a2 * nn + b0.z, a3 * nn + b0.w};
        f4 r1 = {a4 * nn + b1.x, a5 * nn + b1.y, a6 * nn + b1.z, a7 * nn + b1.w};
        *(f4*)(out + (size_t)node * 64 + col) = r0;
        *(f4*)(out + (size_t)node * 64 + col + 4) = r1;
    }
}

extern "C" void kernel_launch(void* const* d_in, const int* in_sizes, int n_in,
                              void* d_out, int out_size, void* d_ws, size_t ws_size,
                              hipStream_t stream) {
    const float* feat = (const float*)d_in[0];
    const int*   src  = (const int*)d_in[1];
    const int*   dst  = (const int*)d_in[2];
    const float* ew   = (const float*)d_in[3];
    const float* W0   = (const float*)d_in[4];
    const float* b0   = (const float*)d_in[5];
    const float* W1   = (const float*)d_in[6];
    const float* b1   = (const float*)d_in[7];
    const float* W2   = (const float*)d_in[8];
    const float* b2   = (const float*)d_in[9];
    float* out = (float*)d_out;

    const int N = in_sizes[0] / 128;
    const int E = in_sizes[1];
    const int NB = (N + 255) / 256;
    const int B1 = (E + EPB - 1) / EPB;

    uint8_t* wp = (uint8_t*)d_ws;
    auto alloc = [&](size_t bytes) {
        uint8_t* r = wp;
        wp += (bytes + 511) & ~(size_t)511;
        return r;
    };
    u16*   featb = (u16*)alloc((size_t)N * 128 * 2);  // layer-0 input; reused as layer-1 output
    u16*   Xb    = (u16*)alloc((size_t)N * 128 * 2);  // aliases prep tables; layer-0 output
    u8*    scr   = (u8*)alloc((size_t)E * 16 + 65536); // prep tdst/tsw/tsrc; later Gb
    int2*  csr   = (int2*)alloc((size_t)E * 8);
    int*   row   = (int*)alloc((size_t)(N + 1) * 4);
    float* onorm = (float*)alloc((size_t)N * 4);
    float* inorm = (float*)alloc((size_t)N * 4);
    u16*   Wt0   = (u16*)alloc(128 * 128 * 2);
    u16*   Wt1   = (u16*)alloc(128 * 128 * 2);
    u16*   Wt2   = (u16*)alloc(128 * 64 * 2);

    // prep-phase aliases inside Xb (dead before Xb first written by layer-0)
    uint8_t* xp = (uint8_t*)Xb;
    auto xalloc = [&](size_t bytes) {
        uint8_t* r = xp;
        xp += (bytes + 511) & ~(size_t)511;
        return r;
    };
    u16* lrank_d = (u16*)xalloc((size_t)E * 2);
    u16* lrank_s = (u16*)xalloc((size_t)E * 2);
    int* bh_d    = (int*)xalloc((size_t)B1 * NB * 4);
    int* bh_s    = (int*)xalloc((size_t)B1 * NB * 4);
    int* cb_d    = (int*)xalloc((size_t)NB * 4);
    int* cb_s    = (int*)xalloc((size_t)NB * 4);
    int* bktb_d  = (int*)xalloc((size_t)NB * 4);
    int* bktb_s  = (int*)xalloc((size_t)NB * 4);

    // prep tables + layer-2 G inside scr (prep dead before Gb written)
    uint8_t* yp = scr;
    auto yalloc = [&](size_t bytes) {
        uint8_t* r = yp;
        yp += (bytes + 511) & ~(size_t)511;
        return r;
    };
    u8*   tdst = (u8*)yalloc((size_t)E);
    int2* tsw  = (int2*)yalloc((size_t)E * 8);
    u8*   tsrc = (u8*)yalloc((size_t)E);
    u16*  Gb   = (u16*)scr;   // written by mgemm64 after prep complete

    // ---- conversions + CSR build (LDS atomics only) ----
    k_cvt<<<(N * 128 / 8 + 255) / 256, 256, 0, stream>>>(feat, featb, N * 128 / 8);
    k_wcvt3<<<160, 256, 0, stream>>>(W0, W1, W2, Wt0, Wt1, Wt2);
    k_p1<<<B1, 256, 0, stream>>>(src, dst, lrank_s, lrank_d, bh_s, bh_d, NB, E);
    k_p2<<<dim3(NB, 2), 512, 0, stream>>>(bh_d, bh_s, cb_d, cb_s, NB, B1);
    k_p2b<<<1, 512, 0, stream>>>(cb_d, cb_s, bktb_d, bktb_s, row, NB, N, E);
    k_p3<<<B1, 256, 0, stream>>>(src, dst, ew, lrank_s, lrank_d, bh_s, bh_d,
                                 bktb_s, bktb_d, tdst, tsw, tsrc, NB, E);
    k_p4s<<<NB, 256, 0, stream>>>(tsrc, bktb_s, cb_s, onorm, NB, N);
    k_p4d<<<NB, 256, 0, stream>>>(tdst, tsw, bktb_d, cb_d, onorm, row, inorm,
                                  csr, NB, N);

    // ---- 3 GraphConv layers ----
    const int fb = (N + 63) / 64;
    const int ab = (N + 3) / 4;

    k_aggemm<true><<<fb, 256, 0, stream>>>(featb, row, csr, inorm, Wt0, b0, Xb, N);
    k_aggemm<true><<<fb, 256, 0, stream>>>(Xb, row, csr, inorm, Wt1, b1, featb, N);
    k_mgemm64<<<fb, 256, 0, stream>>>(featb, Wt2, Gb, N);
    k_agg64b<<<ab, 256, 0, stream>>>(Gb, row, csr, inorm, b2, out, N);
}

// Round 8
// 313.414 us; speedup vs baseline: 1.1262x; 1.1262x over previous
//
#include <hip/hip_runtime.h>
#include <cstddef>
#include <cstdint>

typedef float f4 __attribute__((ext_vector_type(4)));
typedef unsigned long long u64;
typedef unsigned short u16;
typedef unsigned char u8;
typedef unsigned short u16x8 __attribute__((ext_vector_type(8)));
typedef short short8 __attribute__((ext_vector_type(8)));

__device__ __forceinline__ u64 ldnt8(const void* p) {
    return __builtin_nontemporal_load((const u64*)(p));
}
// bf16 round-to-nearest-even
__device__ __forceinline__ u16 bfrn(float f) {
    unsigned u = __float_as_uint(f);
    return (u16)((u + 0x7FFFu + ((u >> 16) & 1u)) >> 16);
}
__device__ __forceinline__ float bl(unsigned w) { return __uint_as_float(w << 16); }
__device__ __forceinline__ float bh(unsigned w) { return __uint_as_float(w & 0xFFFF0000u); }

// ---------------------------------------------------------------------------
// GraphConv x3 (DGL norm='both', per-edge weight)
//   coef[e] = ew[e] * out_norm[src[e]]  (fused into CSR)
// CSR build: two-level counting sort (LDS atomics only).
//   p1: per-block coarse histograms only (no rank materialization)
//   p3: recomputes local ranks in LDS; scatters tsw={dstlo<<24|src, ew}, tsrc=u8
//   p4s/p4d: per-bucket fine count/scan/scatter -> norms + csr
// Layers: split agg (bf16 gather, fp32 acc) + MFMA GEMM (round-6 proven).
// Buffers ping-pong: featb -> [agg] tmp -> [gemm] Xb -> [agg] tmp -> [gemm]
// featb -> [gemm64] Gb -> [agg64] out.
// ---------------------------------------------------------------------------

#define EPB 4096

__global__ void __launch_bounds__(256)
k_p1(const int* __restrict__ src, const int* __restrict__ dst,
     int* __restrict__ bh_s, int* __restrict__ bh_d, int NB, int E) {
    __shared__ int hs[512], hd[512];
    const int t = threadIdx.x, b = blockIdx.x;
    for (int i = t; i < 512; i += 256) { hs[i] = 0; hd[i] = 0; }
    __syncthreads();
    const int e0 = b * EPB;
    #pragma unroll
    for (int j = 0; j < 4; ++j) {
        const int e = e0 + j * 1024 + t * 4;
        if (e + 4 <= E) {
            const int4 d = *(const int4*)&dst[e];
            const int4 s = *(const int4*)&src[e];
            atomicAdd(&hd[d.x >> 8], 1);
            atomicAdd(&hd[d.y >> 8], 1);
            atomicAdd(&hd[d.z >> 8], 1);
            atomicAdd(&hd[d.w >> 8], 1);
            atomicAdd(&hs[s.x >> 8], 1);
            atomicAdd(&hs[s.y >> 8], 1);
            atomicAdd(&hs[s.z >> 8], 1);
            atomicAdd(&hs[s.w >> 8], 1);
        } else {
            for (int k = e; k < E && k < e + 4; ++k) {
                atomicAdd(&hd[dst[k] >> 8], 1);
                atomicAdd(&hs[src[k] >> 8], 1);
            }
        }
    }
    __syncthreads();
    for (int i = t; i < NB; i += 256) {
        bh_d[b * NB + i] = hd[i];
        bh_s[b * NB + i] = hs[i];
    }
}

__global__ void __launch_bounds__(512)
k_p2(int* __restrict__ bh_d, int* __restrict__ bh_s,
     int* __restrict__ cb_d, int* __restrict__ cb_s, int NB, int B1) {
    __shared__ int s[512];
    const int B = blockIdx.x, i = threadIdx.x;
    int* bh = blockIdx.y ? bh_s : bh_d;
    int* cb = blockIdx.y ? cb_s : cb_d;
    const int v = (i < B1) ? bh[i * NB + B] : 0;
    s[i] = v;
    __syncthreads();
    for (int off = 1; off < 512; off <<= 1) {
        const int x = (i >= off) ? s[i - off] : 0;
        __syncthreads();
        s[i] += x;
        __syncthreads();
    }
    if (i < B1) bh[i * NB + B] = s[i] - v;
    if (i == 511) cb[B] = s[511];
}

__global__ void __launch_bounds__(512)
k_p2b(const int* __restrict__ cb_d, const int* __restrict__ cb_s,
      int* __restrict__ bktb_d, int* __restrict__ bktb_s,
      int* __restrict__ row, int NB, int N, int E) {
    __shared__ int s[512];
    const int t = threadIdx.x;
    int v = (t < NB) ? cb_d[t] : 0;
    s[t] = v;
    __syncthreads();
    for (int off = 1; off < 512; off <<= 1) {
        const int x = (t >= off) ? s[t - off] : 0;
        __syncthreads();
        s[t] += x;
        __syncthreads();
    }
    if (t < NB) bktb_d[t] = s[t] - v;
    __syncthreads();
    v = (t < NB) ? cb_s[t] : 0;
    s[t] = v;
    __syncthreads();
    for (int off = 1; off < 512; off <<= 1) {
        const int x = (t >= off) ? s[t - off] : 0;
        __syncthreads();
        s[t] += x;
        __syncthreads();
    }
    if (t < NB) bktb_s[t] = s[t] - v;
    if (t == 0) row[N] = E;
}

__global__ void __launch_bounds__(256)
k_p3(const int* __restrict__ src, const int* __restrict__ dst,
     const float* __restrict__ ew,
     const int* __restrict__ bh_s, const int* __restrict__ bh_d,
     const int* __restrict__ bktb_s, const int* __restrict__ bktb_d,
     int2* __restrict__ tsw, u8* __restrict__ tsrc, int NB, int E) {
    __shared__ int hs[512], hd[512], base_s[512], base_d[512];
    const int t = threadIdx.x, b = blockIdx.x;
    for (int i = t; i < 512; i += 256) {
        hs[i] = 0; hd[i] = 0;
        if (i < NB) {
            base_d[i] = bktb_d[i] + bh_d[b * NB + i];
            base_s[i] = bktb_s[i] + bh_s[b * NB + i];
        }
    }
    __syncthreads();
    const int e0 = b * EPB;
    #pragma unroll
    for (int j = 0; j < 4; ++j) {
        const int e = e0 + j * 1024 + t * 4;
        if (e + 4 <= E) {
            const int4 d = *(const int4*)&dst[e];
            const int4 s = *(const int4*)&src[e];
            const f4   w = *(const f4*)&ew[e];
            const int dd[4] = {d.x, d.y, d.z, d.w};
            const int ss[4] = {s.x, s.y, s.z, s.w};
            const float ww[4] = {w.x, w.y, w.z, w.w};
            #pragma unroll
            for (int k = 0; k < 4; ++k) {
                const int Bd = dd[k] >> 8;
                const int rd = atomicAdd(&hd[Bd], 1);
                tsw[base_d[Bd] + rd] = make_int2(ss[k] | ((dd[k] & 255) << 24),
                                                 __float_as_int(ww[k]));
                const int Bs = ss[k] >> 8;
                const int rs = atomicAdd(&hs[Bs], 1);
                tsrc[base_s[Bs] + rs] = (u8)(ss[k] & 255);
            }
        } else {
            for (int k = e; k < E && k < e + 4; ++k) {
                const int dv = dst[k], sv = src[k];
                const int Bd = dv >> 8;
                const int rd = atomicAdd(&hd[Bd], 1);
                tsw[base_d[Bd] + rd] = make_int2(sv | ((dv & 255) << 24),
                                                 __float_as_int(ew[k]));
                const int Bs = sv >> 8;
                const int rs = atomicAdd(&hs[Bs], 1);
                tsrc[base_s[Bs] + rs] = (u8)(sv & 255);
            }
        }
    }
}

__global__ void __launch_bounds__(256)
k_p4s(const u8* __restrict__ tsrc, const int* __restrict__ bktb_s,
      const int* __restrict__ cb_s, float* __restrict__ onorm, int NB, int N) {
    __shared__ int cnt[256];
    const int B = blockIdx.x, t = threadIdx.x;
    cnt[t] = 0;
    __syncthreads();
    const int base = bktb_s[B], cb = cb_s[B];
    for (int i = t; i < cb; i += 256) atomicAdd(&cnt[tsrc[base + i]], 1);
    __syncthreads();
    const int n = (B << 8) + t;
    if (n < N) {
        const int c = cnt[t];
        onorm[n] = rsqrtf((float)(c < 1 ? 1 : c));
    }
}

__global__ void __launch_bounds__(256)
k_p4d(const int2* __restrict__ tsw,
      const int* __restrict__ bktb_d, const int* __restrict__ cb_d,
      const float* __restrict__ onorm, int* __restrict__ row,
      float* __restrict__ inorm, int2* __restrict__ csr, int NB, int N) {
    __shared__ int cnt[256], cnt2[256], lrow[256], sc[256];
    const int B = blockIdx.x, t = threadIdx.x;
    cnt[t] = 0; cnt2[t] = 0;
    __syncthreads();
    const int base = bktb_d[B], cb = cb_d[B];
    for (int i = t; i < cb; i += 256)
        atomicAdd(&cnt[((unsigned)tsw[base + i].x) >> 24], 1);
    __syncthreads();
    const int v = cnt[t];
    sc[t] = v;
    __syncthreads();
    for (int off = 1; off < 256; off <<= 1) {
        const int x = (t >= off) ? sc[t - off] : 0;
        __syncthreads();
        sc[t] += x;
        __syncthreads();
    }
    const int excl = sc[t] - v;
    lrow[t] = excl;
    const int n = (B << 8) + t;
    if (n < N) {
        row[n] = base + excl;
        inorm[n] = rsqrtf((float)(v < 1 ? 1 : v));
    }
    __syncthreads();
    for (int i = t; i < cb; i += 256) {
        const int2 sw = tsw[base + i];
        const int d = ((unsigned)sw.x) >> 24;
        const int s = sw.x & 0xFFFFFF;
        const int r = atomicAdd(&cnt2[d], 1);
        const float coef = __int_as_float(sw.y) * onorm[s];
        csr[base + lrow[d] + r] = make_int2(s, __float_as_int(coef));
    }
}

__global__ void __launch_bounds__(256)
k_cvt(const float* __restrict__ in, u16* __restrict__ out, int n8) {
    const int i = blockIdx.x * blockDim.x + threadIdx.x;
    if (i < n8) {
        const f4 v0 = *(const f4*)(in + (size_t)i * 8);
        const f4 v1 = *(const f4*)(in + (size_t)i * 8 + 4);
        u16x8 r = {bfrn(v0.x), bfrn(v0.y), bfrn(v0.z), bfrn(v0.w),
                   bfrn(v1.x), bfrn(v1.y), bfrn(v1.z), bfrn(v1.w)};
        *(u16x8*)(out + (size_t)i * 8) = r;
    }
}

__global__ void __launch_bounds__(256)
k_wcvt3(const float* __restrict__ W0, const float* __restrict__ W1,
        const float* __restrict__ W2, u16* __restrict__ Wt0,
        u16* __restrict__ Wt1, u16* __restrict__ Wt2) {
    const int i = blockIdx.x * 256 + threadIdx.x;
    if (i < 16384) {
        const int k = i >> 7, c = i & 127;
        Wt0[c * 128 + k] = bfrn(W0[i]);
    } else if (i < 32768) {
        const int j = i - 16384, k = j >> 7, c = j & 127;
        Wt1[c * 128 + k] = bfrn(W1[j]);
    } else if (i < 40960) {
        const int j = i - 32768, k = j >> 6, c = j & 63;
        Wt2[c * 128 + k] = bfrn(W2[j]);
    }
}

// one wave per node, width 128 bf16: quarter-wave per edge, 16 edges/iter
__global__ void __launch_bounds__(256)
k_agg128b(const u16* __restrict__ h, const int* __restrict__ row,
          const int2* __restrict__ csr, const float* __restrict__ inorm,
          u16* __restrict__ out, int N) {
    const int node = (int)((blockIdx.x * blockDim.x + threadIdx.x) >> 6);
    if (node >= N) return;
    const int lane = threadIdx.x & 63;
    const int q = lane >> 4;
    const int col = (lane & 15) * 8;
    int p = row[node];
    const int e = row[node + 1];
    float a0 = 0, a1 = 0, a2 = 0, a3 = 0, a4 = 0, a5 = 0, a6 = 0, a7 = 0;
    for (; p + 16 <= e; p += 16) {
        const u64 c0 = ldnt8(&csr[p + q]);
        const u64 c1 = ldnt8(&csr[p + 4 + q]);
        const u64 c2 = ldnt8(&csr[p + 8 + q]);
        const u64 c3 = ldnt8(&csr[p + 12 + q]);
        const uint4 w0 = *(const uint4*)(h + (size_t)(int)c0 * 128 + col);
        const uint4 w1 = *(const uint4*)(h + (size_t)(int)c1 * 128 + col);
        const uint4 w2 = *(const uint4*)(h + (size_t)(int)c2 * 128 + col);
        const uint4 w3 = *(const uint4*)(h + (size_t)(int)c3 * 128 + col);
        const float f0 = __int_as_float((int)(c0 >> 32));
        const float f1 = __int_as_float((int)(c1 >> 32));
        const float f2 = __int_as_float((int)(c2 >> 32));
        const float f3 = __int_as_float((int)(c3 >> 32));
        a0 = fmaf(f0, bl(w0.x), a0); a1 = fmaf(f0, bh(w0.x), a1);
        a2 = fmaf(f0, bl(w0.y), a2); a3 = fmaf(f0, bh(w0.y), a3);
        a4 = fmaf(f0, bl(w0.z), a4); a5 = fmaf(f0, bh(w0.z), a5);
        a6 = fmaf(f0, bl(w0.w), a6); a7 = fmaf(f0, bh(w0.w), a7);
        a0 = fmaf(f1, bl(w1.x), a0); a1 = fmaf(f1, bh(w1.x), a1);
        a2 = fmaf(f1, bl(w1.y), a2); a3 = fmaf(f1, bh(w1.y), a3);
        a4 = fmaf(f1, bl(w1.z), a4); a5 = fmaf(f1, bh(w1.z), a5);
        a6 = fmaf(f1, bl(w1.w), a6); a7 = fmaf(f1, bh(w1.w), a7);
        a0 = fmaf(f2, bl(w2.x), a0); a1 = fmaf(f2, bh(w2.x), a1);
        a2 = fmaf(f2, bl(w2.y), a2); a3 = fmaf(f2, bh(w2.y), a3);
        a4 = fmaf(f2, bl(w2.z), a4); a5 = fmaf(f2, bh(w2.z), a5);
        a6 = fmaf(f2, bl(w2.w), a6); a7 = fmaf(f2, bh(w2.w), a7);
        a0 = fmaf(f3, bl(w3.x), a0); a1 = fmaf(f3, bh(w3.x), a1);
        a2 = fmaf(f3, bl(w3.y), a2); a3 = fmaf(f3, bh(w3.y), a3);
        a4 = fmaf(f3, bl(w3.z), a4); a5 = fmaf(f3, bh(w3.z), a5);
        a6 = fmaf(f3, bl(w3.w), a6); a7 = fmaf(f3, bh(w3.w), a7);
    }
    for (; p + 8 <= e; p += 8) {
        const u64 c0 = ldnt8(&csr[p + q]);
        const u64 c1 = ldnt8(&csr[p + 4 + q]);
        const uint4 w0 = *(const uint4*)(h + (size_t)(int)c0 * 128 + col);
        const uint4 w1 = *(const uint4*)(h + (size_t)(int)c1 * 128 + col);
        const float f0 = __int_as_float((int)(c0 >> 32));
        const float f1 = __int_as_float((int)(c1 >> 32));
        a0 = fmaf(f0, bl(w0.x), a0); a1 = fmaf(f0, bh(w0.x), a1);
        a2 = fmaf(f0, bl(w0.y), a2); a3 = fmaf(f0, bh(w0.y), a3);
        a4 = fmaf(f0, bl(w0.z), a4); a5 = fmaf(f0, bh(w0.z), a5);
        a6 = fmaf(f0, bl(w0.w), a6); a7 = fmaf(f0, bh(w0.w), a7);
        a0 = fmaf(f1, bl(w1.x), a0); a1 = fmaf(f1, bh(w1.x), a1);
        a2 = fmaf(f1, bl(w1.y), a2); a3 = fmaf(f1, bh(w1.y), a3);
        a4 = fmaf(f1, bl(w1.z), a4); a5 = fmaf(f1, bh(w1.z), a5);
        a6 = fmaf(f1, bl(w1.w), a6); a7 = fmaf(f1, bh(w1.w), a7);
    }
    {
        const int i0 = p + q, i1 = p + 4 + q;
        if (i0 < e) {
            const u64 c = ldnt8(&csr[i0]);
            const uint4 w = *(const uint4*)(h + (size_t)(int)c * 128 + col);
            const float f = __int_as_float((int)(c >> 32));
            a0 = fmaf(f, bl(w.x), a0); a1 = fmaf(f, bh(w.x), a1);
            a2 = fmaf(f, bl(w.y), a2); a3 = fmaf(f, bh(w.y), a3);
            a4 = fmaf(f, bl(w.z), a4); a5 = fmaf(f, bh(w.z), a5);
            a6 = fmaf(f, bl(w.w), a6); a7 = fmaf(f, bh(w.w), a7);
        }
        if (i1 < e) {
            const u64 c = ldnt8(&csr[i1]);
            const uint4 w = *(const uint4*)(h + (size_t)(int)c * 128 + col);
            const float f = __int_as_float((int)(c >> 32));
            a0 = fmaf(f, bl(w.x), a0); a1 = fmaf(f, bh(w.x), a1);
            a2 = fmaf(f, bl(w.y), a2); a3 = fmaf(f, bh(w.y), a3);
            a4 = fmaf(f, bl(w.z), a4); a5 = fmaf(f, bh(w.z), a5);
            a6 = fmaf(f, bl(w.w), a6); a7 = fmaf(f, bh(w.w), a7);
        }
    }
    a0 += __shfl_xor(a0, 16); a1 += __shfl_xor(a1, 16);
    a2 += __shfl_xor(a2, 16); a3 += __shfl_xor(a3, 16);
    a4 += __shfl_xor(a4, 16); a5 += __shfl_xor(a5, 16);
    a6 += __shfl_xor(a6, 16); a7 += __shfl_xor(a7, 16);
    a0 += __shfl_xor(a0, 32); a1 += __shfl_xor(a1, 32);
    a2 += __shfl_xor(a2, 32); a3 += __shfl_xor(a3, 32);
    a4 += __shfl_xor(a4, 32); a5 += __shfl_xor(a5, 32);
    a6 += __shfl_xor(a6, 32); a7 += __shfl_xor(a7, 32);
    if (lane < 16) {
        const float nn = inorm[node];
        u16x8 r = {bfrn(a0 * nn), bfrn(a1 * nn), bfrn(a2 * nn), bfrn(a3 * nn),
                   bfrn(a4 * nn), bfrn(a5 * nn), bfrn(a6 * nn), bfrn(a7 * nn)};
        *(u16x8*)(out + (size_t)node * 128 + col) = r;
    }
}

// one wave per node, width 64 bf16: eighth-wave per edge; fused bias; fp32 out
__global__ void __launch_bounds__(256)
k_agg64b(const u16* __restrict__ h, const int* __restrict__ row,
         const int2* __restrict__ csr, const float* __restrict__ inorm,
         const float* __restrict__ bias, float* __restrict__ out, int N) {
    const int node = (int)((blockIdx.x * blockDim.x + threadIdx.x) >> 6);
    if (node >= N) return;
    const int lane = threadIdx.x & 63;
    const int oc = lane >> 3;
    const int col = (lane & 7) * 8;
    int p = row[node];
    const int e = row[node + 1];
    float a0 = 0, a1 = 0, a2 = 0, a3 = 0, a4 = 0, a5 = 0, a6 = 0, a7 = 0;
    for (; p + 16 <= e; p += 16) {
        const u64 c0 = ldnt8(&csr[p + oc]);
        const u64 c1 = ldnt8(&csr[p + 8 + oc]);
        const uint4 w0 = *(const uint4*)(h + (size_t)(int)c0 * 64 + col);
        const uint4 w1 = *(const uint4*)(h + (size_t)(int)c1 * 64 + col);
        const float f0 = __int_as_float((int)(c0 >> 32));
        const float f1 = __int_as_float((int)(c1 >> 32));
        a0 = fmaf(f0, bl(w0.x), a0); a1 = fmaf(f0, bh(w0.x), a1);
        a2 = fmaf(f0, bl(w0.y), a2); a3 = fmaf(f0, bh(w0.y), a3);
        a4 = fmaf(f0, bl(w0.z), a4); a5 = fmaf(f0, bh(w0.z), a5);
        a6 = fmaf(f0, bl(w0.w), a6); a7 = fmaf(f0, bh(w0.w), a7);
        a0 = fmaf(f1, bl(w1.x), a0); a1 = fmaf(f1, bh(w1.x), a1);
        a2 = fmaf(f1, bl(w1.y), a2); a3 = fmaf(f1, bh(w1.y), a3);
        a4 = fmaf(f1, bl(w1.z), a4); a5 = fmaf(f1, bh(w1.z), a5);
        a6 = fmaf(f1, bl(w1.w), a6); a7 = fmaf(f1, bh(w1.w), a7);
    }
    {
        const int i0 = p + oc, i1 = p + 8 + oc;
        if (i0 < e) {
            const u64 c = ldnt8(&csr[i0]);
            const uint4 w = *(const uint4*)(h + (size_t)(int)c * 64 + col);
            const float f = __int_as_float((int)(c >> 32));
            a0 = fmaf(f, bl(w.x), a0); a1 = fmaf(f, bh(w.x), a1);
            a2 = fmaf(f, bl(w.y), a2); a3 = fmaf(f, bh(w.y), a3);
            a4 = fmaf(f, bl(w.z), a4); a5 = fmaf(f, bh(w.z), a5);
            a6 = fmaf(f, bl(w.w), a6); a7 = fmaf(f, bh(w.w), a7);
        }
        if (i1 < e) {
            const u64 c = ldnt8(&csr[i1]);
            const uint4 w = *(const uint4*)(h + (size_t)(int)c * 64 + col);
            const float f = __int_as_float((int)(c >> 32));
            a0 = fmaf(f, bl(w.x), a0); a1 = fmaf(f, bh(w.x), a1);
            a2 = fmaf(f, bl(w.y), a2); a3 = fmaf(f, bh(w.y), a3);
            a4 = fmaf(f, bl(w.z), a4); a5 = fmaf(f, bh(w.z), a5);
            a6 = fmaf(f, bl(w.w), a6); a7 = fmaf(f, bh(w.w), a7);
        }
    }
    a0 += __shfl_xor(a0, 8);  a1 += __shfl_xor(a1, 8);
    a2 += __shfl_xor(a2, 8);  a3 += __shfl_xor(a3, 8);
    a4 += __shfl_xor(a4, 8);  a5 += __shfl_xor(a5, 8);
    a6 += __shfl_xor(a6, 8);  a7 += __shfl_xor(a7, 8);
    a0 += __shfl_xor(a0, 16); a1 += __shfl_xor(a1, 16);
    a2 += __shfl_xor(a2, 16); a3 += __shfl_xor(a3, 16);
    a4 += __shfl_xor(a4, 16); a5 += __shfl_xor(a5, 16);
    a6 += __shfl_xor(a6, 16); a7 += __shfl_xor(a7, 16);
    a0 += __shfl_xor(a0, 32); a1 += __shfl_xor(a1, 32);
    a2 += __shfl_xor(a2, 32); a3 += __shfl_xor(a3, 32);
    a4 += __shfl_xor(a4, 32); a5 += __shfl_xor(a5, 32);
    a6 += __shfl_xor(a6, 32); a7 += __shfl_xor(a7, 32);
    if (lane < 8) {
        const float nn = inorm[node];
        const f4 b0 = *(const f4*)(bias + col);
        const f4 b1 = *(const f4*)(bias + col + 4);
        f4 r0 = {a0 * nn + b0.x, a1 * nn + b0.y, a2 * nn + b0.z, a3 * nn + b0.w};
        f4 r1 = {a4 * nn + b1.x, a5 * nn + b1.y, a6 * nn + b1.z, a7 * nn + b1.w};
        *(f4*)(out + (size_t)node * 64 + col) = r0;
        *(f4*)(out + (size_t)node * 64 + col + 4) = r1;
    }
}

// MFMA GEMM: C[N x COLS] = A[N x 128] @ W[128 x COLS] (+bias,+relu), bf16 io.
template <int COLS, bool RELU, bool BIAS>
__global__ void __launch_bounds__(256)
k_mgemm(const u16* __restrict__ A, const u16* __restrict__ Wt,
        const float* __restrict__ bias, u16* __restrict__ C, int N) {
    __shared__ u16 Wl[COLS][136];
    const int t = threadIdx.x;
    const int lane = t & 63;
    const int wave = t >> 6;
    #pragma unroll
    for (int i = 0; i < COLS / 16; ++i) {
        const int elem = (i * 256 + t) * 8;
        const int r = elem >> 7, c0 = elem & 127;
        *(short8*)&Wl[r][c0] = *(const short8*)(Wt + elem);
    }
    const int row0 = blockIdx.x * 64 + wave * 16;
    const int arow = min(row0 + (lane & 15), N - 1);
    const int koff = (lane >> 4) * 8;
    short8 a[4];
    #pragma unroll
    for (int kk = 0; kk < 4; ++kk)
        a[kk] = *(const short8*)(A + (size_t)arow * 128 + kk * 32 + koff);
    __syncthreads();

    f4 acc[COLS / 16];
    #pragma unroll
    for (int ct = 0; ct < COLS / 16; ++ct) acc[ct] = (f4){0.f, 0.f, 0.f, 0.f};

    #pragma unroll
    for (int ct = 0; ct < COLS / 16; ++ct) {
        #pragma unroll
        for (int kk = 0; kk < 4; ++kk) {
            const short8 b = *(const short8*)&Wl[ct * 16 + (lane & 15)][kk * 32 + koff];
            acc[ct] = __builtin_amdgcn_mfma_f32_16x16x32_bf16(a[kk], b, acc[ct], 0, 0, 0);
        }
    }

    #pragma unroll
    for (int ct = 0; ct < COLS / 16; ++ct) {
        const int c = ct * 16 + (lane & 15);
        const float bb = BIAS ? bias[c] : 0.f;
        #pragma unroll
        for (int r = 0; r < 4; ++r) {
            const int gr = row0 + (lane >> 4) * 4 + r;
            if (gr < N) {
                float v = acc[ct][r] + bb;
                if (RELU) v = v > 0.f ? v : 0.f;
                C[(size_t)gr * COLS + c] = bfrn(v);
            }
        }
    }
}

extern "C" void kernel_launch(void* const* d_in, const int* in_sizes, int n_in,
                              void* d_out, int out_size, void* d_ws, size_t ws_size,
                              hipStream_t stream) {
    const float* feat = (const float*)d_in[0];
    const int*   src  = (const int*)d_in[1];
    const int*   dst  = (const int*)d_in[2];
    const float* ew   = (const float*)d_in[3];
    const float* W0   = (const float*)d_in[4];
    const float* b0   = (const float*)d_in[5];
    const float* W1   = (const float*)d_in[6];
    const float* b1   = (const float*)d_in[7];
    const float* W2   = (const float*)d_in[8];
    const float* b2   = (const float*)d_in[9];
    float* out = (float*)d_out;

    const int N = in_sizes[0] / 128;
    const int E = in_sizes[1];
    const int NB = (N + 255) / 256;
    const int B1 = (E + EPB - 1) / EPB;

    uint8_t* wp = (uint8_t*)d_ws;
    auto alloc = [&](size_t bytes) {
        uint8_t* r = wp;
        wp += (bytes + 511) & ~(size_t)511;
        return r;
    };
    u16*   featb = (u16*)alloc((size_t)N * 128 * 2);  // layer-0 input / layer-1 GEMM input
    u16*   Xb    = (u16*)alloc((size_t)N * 128 * 2);  // aliases prep hists
    u16*   Tb    = (u16*)alloc((size_t)N * 128 * 2);  // agg output (ping)
    u8*    scr   = (u8*)alloc((size_t)E * 10 + 65536); // tsw+tsrc; later Gb
    int2*  csr   = (int2*)alloc((size_t)E * 8);
    int*   row   = (int*)alloc((size_t)(N + 1) * 4);
    float* onorm = (float*)alloc((size_t)N * 4);
    float* inorm = (float*)alloc((size_t)N * 4);
    u16*   Wt0   = (u16*)alloc(128 * 128 * 2);
    u16*   Wt1   = (u16*)alloc(128 * 128 * 2);
    u16*   Wt2   = (u16*)alloc(128 * 64 * 2);

    // prep-phase aliases inside Xb (dead before Xb first written by layer-0 GEMM)
    uint8_t* xp = (uint8_t*)Xb;
    auto xalloc = [&](size_t bytes) {
        uint8_t* r = xp;
        xp += (bytes + 511) & ~(size_t)511;
        return r;
    };
    int* bh_d   = (int*)xalloc((size_t)B1 * NB * 4);
    int* bh_s   = (int*)xalloc((size_t)B1 * NB * 4);
    int* cb_d   = (int*)xalloc((size_t)NB * 4);
    int* cb_s   = (int*)xalloc((size_t)NB * 4);
    int* bktb_d = (int*)xalloc((size_t)NB * 4);
    int* bktb_s = (int*)xalloc((size_t)NB * 4);

    // prep tables + layer-2 G inside scr
    uint8_t* yp = scr;
    auto yalloc = [&](size_t bytes) {
        uint8_t* r = yp;
        yp += (bytes + 511) & ~(size_t)511;
        return r;
    };
    int2* tsw  = (int2*)yalloc((size_t)E * 8);
    u8*   tsrc = (u8*)yalloc((size_t)E);
    u16*  Gb   = (u16*)scr;   // written by layer-2 GEMM after prep complete

    // ---- conversions + CSR build (LDS atomics only) ----
    k_cvt<<<(N * 128 / 8 + 255) / 256, 256, 0, stream>>>(feat, featb, N * 128 / 8);
    k_wcvt3<<<160, 256, 0, stream>>>(W0, W1, W2, Wt0, Wt1, Wt2);
    k_p1<<<B1, 256, 0, stream>>>(src, dst, bh_s, bh_d, NB, E);
    k_p2<<<dim3(NB, 2), 512, 0, stream>>>(bh_d, bh_s, cb_d, cb_s, NB, B1);
    k_p2b<<<1, 512, 0, stream>>>(cb_d, cb_s, bktb_d, bktb_s, row, NB, N, E);
    k_p3<<<B1, 256, 0, stream>>>(src, dst, ew, bh_s, bh_d, bktb_s, bktb_d,
                                 tsw, tsrc, NB, E);
    k_p4s<<<NB, 256, 0, stream>>>(tsrc, bktb_s, cb_s, onorm, NB, N);
    k_p4d<<<NB, 256, 0, stream>>>(tsw, bktb_d, cb_d, onorm, row, inorm, csr, NB, N);

    // ---- 3 GraphConv layers ----
    const int ab = (N + 3) / 4;
    const int gb = (N + 63) / 64;

    // layer 0: agg(featb) -> Tb ; Xb = relu(Tb@W0 + b0)
    k_agg128b<<<ab, 256, 0, stream>>>(featb, row, csr, inorm, Tb, N);
    k_mgemm<128, true, true><<<gb, 256, 0, stream>>>(Tb, Wt0, b0, Xb, N);
    // layer 1: agg(Xb) -> Tb ; featb = relu(Tb@W1 + b1)
    k_agg128b<<<ab, 256, 0, stream>>>(Xb, row, csr, inorm, Tb, N);
    k_mgemm<128, true, true><<<gb, 256, 0, stream>>>(Tb, Wt1, b1, featb, N);
    // layer 2: Gb = featb@W2 ; out = inorm .* agg(Gb) + b2
    k_mgemm<64, false, false><<<gb, 256, 0, stream>>>(featb, Wt2, nullptr, Gb, N);
    k_agg64b<<<ab, 256, 0, stream>>>(Gb, row, csr, inorm, b2, out, N);
}

// Round 9
// 311.281 us; speedup vs baseline: 1.1339x; 1.0069x over previous
//
#include <hip/hip_runtime.h>
#include <cstddef>
#include <cstdint>

typedef float f4 __attribute__((ext_vector_type(4)));
typedef unsigned long long u64;
typedef unsigned short u16;
typedef unsigned char u8;
typedef unsigned short u16x8 __attribute__((ext_vector_type(8)));
typedef short short8 __attribute__((ext_vector_type(8)));

__device__ __forceinline__ u64 ldnt8(const void* p) {
    return __builtin_nontemporal_load((const u64*)(p));
}
// bf16 round-to-nearest-even
__device__ __forceinline__ u16 bfrn(float f) {
    unsigned u = __float_as_uint(f);
    return (u16)((u + 0x7FFFu + ((u >> 16) & 1u)) >> 16);
}
__device__ __forceinline__ float bl(unsigned w) { return __uint_as_float(w << 16); }
__device__ __forceinline__ float bh(unsigned w) { return __uint_as_float(w & 0xFFFF0000u); }

// ---------------------------------------------------------------------------
// GraphConv x3 (DGL norm='both', per-edge weight)
//   coef[e] = ew[e] * out_norm[src[e]]  (fused into CSR)
// CSR build: two-level counting sort (LDS atomics only).
//   prep0: fused {feat->bf16 cvt | W->Wt cvt | per-block coarse histograms}
//   p2: coalesced per-bucket scan over blocks (16 buckets/block, LDS tile)
//   p3: recompute local ranks in LDS; scatter tsw={dstlo<<24|src, ew}, tsrc
//   p4s/p4d: per-bucket fine count/scan/scatter -> norms + csr
// Layers: split agg (bf16 gather, fp32 acc) + MFMA GEMM (proven round-6/8).
// ---------------------------------------------------------------------------

#define EPB 4096

// fused: blocks [0,B1) = p1 histograms; [B1,B1+nbcvt) = feat cvt; rest = W cvt
__global__ void __launch_bounds__(256)
k_prep0(const int* __restrict__ src, const int* __restrict__ dst,
        int* __restrict__ bh_s, int* __restrict__ bh_d,
        const float* __restrict__ feat, u16* __restrict__ featb, int n8,
        const float* __restrict__ W0, const float* __restrict__ W1,
        const float* __restrict__ W2, u16* __restrict__ Wt0,
        u16* __restrict__ Wt1, u16* __restrict__ Wt2,
        int NB, int B1, int E) {
    const int bid = blockIdx.x, t = threadIdx.x;
    if (bid < B1) {
        __shared__ int hs[512], hd[512];
        for (int i = t; i < 512; i += 256) { hs[i] = 0; hd[i] = 0; }
        __syncthreads();
        const int e0 = bid * EPB;
        #pragma unroll
        for (int j = 0; j < 4; ++j) {
            const int e = e0 + j * 1024 + t * 4;
            if (e + 4 <= E) {
                const int4 d = *(const int4*)&dst[e];
                const int4 s = *(const int4*)&src[e];
                atomicAdd(&hd[d.x >> 8], 1);
                atomicAdd(&hd[d.y >> 8], 1);
                atomicAdd(&hd[d.z >> 8], 1);
                atomicAdd(&hd[d.w >> 8], 1);
                atomicAdd(&hs[s.x >> 8], 1);
                atomicAdd(&hs[s.y >> 8], 1);
                atomicAdd(&hs[s.z >> 8], 1);
                atomicAdd(&hs[s.w >> 8], 1);
            } else {
                for (int k = e; k < E && k < e + 4; ++k) {
                    atomicAdd(&hd[dst[k] >> 8], 1);
                    atomicAdd(&hs[src[k] >> 8], 1);
                }
            }
        }
        __syncthreads();
        for (int i = t; i < NB; i += 256) {
            bh_d[bid * NB + i] = hd[i];
            bh_s[bid * NB + i] = hs[i];
        }
    } else if (bid < B1 + (n8 + 255) / 256) {
        const int i = (bid - B1) * 256 + t;
        if (i < n8) {
            const f4 v0 = *(const f4*)(feat + (size_t)i * 8);
            const f4 v1 = *(const f4*)(feat + (size_t)i * 8 + 4);
            u16x8 r = {bfrn(v0.x), bfrn(v0.y), bfrn(v0.z), bfrn(v0.w),
                       bfrn(v1.x), bfrn(v1.y), bfrn(v1.z), bfrn(v1.w)};
            *(u16x8*)(featb + (size_t)i * 8) = r;
        }
    } else {
        const int i = (bid - B1 - (n8 + 255) / 256) * 256 + t;
        if (i < 16384) {
            const int k = i >> 7, c = i & 127;
            Wt0[c * 128 + k] = bfrn(W0[i]);
        } else if (i < 32768) {
            const int j = i - 16384, k = j >> 7, c = j & 127;
            Wt1[c * 128 + k] = bfrn(W1[j]);
        } else if (i < 40960) {
            const int j = i - 32768, k = j >> 6, c = j & 63;
            Wt2[c * 128 + k] = bfrn(W2[j]);
        }
    }
}

// P2: per bucket exclusive scan over blocks; coalesced via 512x16 LDS tile.
__global__ void __launch_bounds__(512)
k_p2(int* __restrict__ bh_d, int* __restrict__ bh_s,
     int* __restrict__ cb_d, int* __restrict__ cb_s, int NB, int B1) {
    __shared__ int tile[512][17];
    __shared__ int tot[16];
    const int t = threadIdx.x, lane = t & 63, wave = t >> 6;
    int* bh = blockIdx.y ? bh_s : bh_d;
    int* cb = blockIdx.y ? cb_s : cb_d;
    const int B0 = blockIdx.x * 16;
    #pragma unroll
    for (int j = 0; j < 16; ++j) {
        const int idx = j * 512 + t;
        const int row = idx >> 4, col = idx & 15;
        int v = 0;
        if (row < B1 && B0 + col < NB) v = bh[row * NB + B0 + col];
        tile[row][col] = v;
    }
    __syncthreads();
    #pragma unroll
    for (int cc = 0; cc < 2; ++cc) {
        const int col = wave * 2 + cc;
        int carry = 0;
        #pragma unroll
        for (int ch = 0; ch < 8; ++ch) {
            const int v = tile[ch * 64 + lane][col];
            int s = v;
            #pragma unroll
            for (int d = 1; d < 64; d <<= 1) {
                const int u = __shfl_up(s, d);
                if (lane >= d) s += u;
            }
            tile[ch * 64 + lane][col] = s - v + carry;
            carry += __shfl(s, 63);
        }
        if (lane == 0) tot[col] = carry;
    }
    __syncthreads();
    #pragma unroll
    for (int j = 0; j < 16; ++j) {
        const int idx = j * 512 + t;
        const int row = idx >> 4, col = idx & 15;
        if (row < B1 && B0 + col < NB) bh[row * NB + B0 + col] = tile[row][col];
    }
    if (t < 16 && B0 + t < NB) cb[B0 + t] = tot[t];
}

__global__ void __launch_bounds__(512)
k_p2b(const int* __restrict__ cb_d, const int* __restrict__ cb_s,
      int* __restrict__ bktb_d, int* __restrict__ bktb_s,
      int* __restrict__ row, int NB, int N, int E) {
    __shared__ int s[512];
    const int t = threadIdx.x;
    int v = (t < NB) ? cb_d[t] : 0;
    s[t] = v;
    __syncthreads();
    for (int off = 1; off < 512; off <<= 1) {
        const int x = (t >= off) ? s[t - off] : 0;
        __syncthreads();
        s[t] += x;
        __syncthreads();
    }
    if (t < NB) bktb_d[t] = s[t] - v;
    __syncthreads();
    v = (t < NB) ? cb_s[t] : 0;
    s[t] = v;
    __syncthreads();
    for (int off = 1; off < 512; off <<= 1) {
        const int x = (t >= off) ? s[t - off] : 0;
        __syncthreads();
        s[t] += x;
        __syncthreads();
    }
    if (t < NB) bktb_s[t] = s[t] - v;
    if (t == 0) row[N] = E;
}

__global__ void __launch_bounds__(256)
k_p3(const int* __restrict__ src, const int* __restrict__ dst,
     const float* __restrict__ ew,
     const int* __restrict__ bh_s, const int* __restrict__ bh_d,
     const int* __restrict__ bktb_s, const int* __restrict__ bktb_d,
     int2* __restrict__ tsw, u8* __restrict__ tsrc, int NB, int E) {
    __shared__ int hs[512], hd[512], base_s[512], base_d[512];
    const int t = threadIdx.x, b = blockIdx.x;
    for (int i = t; i < 512; i += 256) {
        hs[i] = 0; hd[i] = 0;
        if (i < NB) {
            base_d[i] = bktb_d[i] + bh_d[b * NB + i];
            base_s[i] = bktb_s[i] + bh_s[b * NB + i];
        }
    }
    __syncthreads();
    const int e0 = b * EPB;
    #pragma unroll
    for (int j = 0; j < 4; ++j) {
        const int e = e0 + j * 1024 + t * 4;
        if (e + 4 <= E) {
            const int4 d = *(const int4*)&dst[e];
            const int4 s = *(const int4*)&src[e];
            const f4   w = *(const f4*)&ew[e];
            const int dd[4] = {d.x, d.y, d.z, d.w};
            const int ss[4] = {s.x, s.y, s.z, s.w};
            const float ww[4] = {w.x, w.y, w.z, w.w};
            #pragma unroll
            for (int k = 0; k < 4; ++k) {
                const int Bd = dd[k] >> 8;
                const int rd = atomicAdd(&hd[Bd], 1);
                tsw[base_d[Bd] + rd] = make_int2(ss[k] | ((dd[k] & 255) << 24),
                                                 __float_as_int(ww[k]));
                const int Bs = ss[k] >> 8;
                const int rs = atomicAdd(&hs[Bs], 1);
                tsrc[base_s[Bs] + rs] = (u8)(ss[k] & 255);
            }
        } else {
            for (int k = e; k < E && k < e + 4; ++k) {
                const int dv = dst[k], sv = src[k];
                const int Bd = dv >> 8;
                const int rd = atomicAdd(&hd[Bd], 1);
                tsw[base_d[Bd] + rd] = make_int2(sv | ((dv & 255) << 24),
                                                 __float_as_int(ew[k]));
                const int Bs = sv >> 8;
                const int rs = atomicAdd(&hs[Bs], 1);
                tsrc[base_s[Bs] + rs] = (u8)(sv & 255);
            }
        }
    }
}

__global__ void __launch_bounds__(256)
k_p4s(const u8* __restrict__ tsrc, const int* __restrict__ bktb_s,
      const int* __restrict__ cb_s, float* __restrict__ onorm, int NB, int N) {
    __shared__ int cnt[256];
    const int B = blockIdx.x, t = threadIdx.x;
    cnt[t] = 0;
    __syncthreads();
    const int base = bktb_s[B], cb = cb_s[B];
    for (int i = t; i < cb; i += 256) atomicAdd(&cnt[tsrc[base + i]], 1);
    __syncthreads();
    const int n = (B << 8) + t;
    if (n < N) {
        const int c = cnt[t];
        onorm[n] = rsqrtf((float)(c < 1 ? 1 : c));
    }
}

__global__ void __launch_bounds__(256)
k_p4d(const int2* __restrict__ tsw,
      const int* __restrict__ bktb_d, const int* __restrict__ cb_d,
      const float* __restrict__ onorm, int* __restrict__ row,
      float* __restrict__ inorm, int2* __restrict__ csr, int NB, int N) {
    __shared__ int cnt[256], cnt2[256], lrow[256], sc[256];
    const int B = blockIdx.x, t = threadIdx.x;
    cnt[t] = 0; cnt2[t] = 0;
    __syncthreads();
    const int base = bktb_d[B], cb = cb_d[B];
    for (int i = t; i < cb; i += 256)
        atomicAdd(&cnt[((unsigned)tsw[base + i].x) >> 24], 1);
    __syncthreads();
    const int v = cnt[t];
    sc[t] = v;
    __syncthreads();
    for (int off = 1; off < 256; off <<= 1) {
        const int x = (t >= off) ? sc[t - off] : 0;
        __syncthreads();
        sc[t] += x;
        __syncthreads();
    }
    const int excl = sc[t] - v;
    lrow[t] = excl;
    const int n = (B << 8) + t;
    if (n < N) {
        row[n] = base + excl;
        inorm[n] = rsqrtf((float)(v < 1 ? 1 : v));
    }
    __syncthreads();
    for (int i = t; i < cb; i += 256) {
        const int2 sw = tsw[base + i];
        const int d = ((unsigned)sw.x) >> 24;
        const int s = sw.x & 0xFFFFFF;
        const int r = atomicAdd(&cnt2[d], 1);
        const float coef = __int_as_float(sw.y) * onorm[s];
        csr[base + lrow[d] + r] = make_int2(s, __float_as_int(coef));
    }
}

// one wave per node, width 128 bf16: quarter-wave per edge, 16 edges/iter
__global__ void __launch_bounds__(256)
k_agg128b(const u16* __restrict__ h, const int* __restrict__ row,
          const int2* __restrict__ csr, const float* __restrict__ inorm,
          u16* __restrict__ out, int N) {
    const int node = (int)((blockIdx.x * blockDim.x + threadIdx.x) >> 6);
    if (node >= N) return;
    const int lane = threadIdx.x & 63;
    const int q = lane >> 4;
    const int col = (lane & 15) * 8;
    int p = row[node];
    const int e = row[node + 1];
    float a0 = 0, a1 = 0, a2 = 0, a3 = 0, a4 = 0, a5 = 0, a6 = 0, a7 = 0;
    for (; p + 16 <= e; p += 16) {
        const u64 c0 = ldnt8(&csr[p + q]);
        const u64 c1 = ldnt8(&csr[p + 4 + q]);
        const u64 c2 = ldnt8(&csr[p + 8 + q]);
        const u64 c3 = ldnt8(&csr[p + 12 + q]);
        const uint4 w0 = *(const uint4*)(h + (size_t)(int)c0 * 128 + col);
        const uint4 w1 = *(const uint4*)(h + (size_t)(int)c1 * 128 + col);
        const uint4 w2 = *(const uint4*)(h + (size_t)(int)c2 * 128 + col);
        const uint4 w3 = *(const uint4*)(h + (size_t)(int)c3 * 128 + col);
        const float f0 = __int_as_float((int)(c0 >> 32));
        const float f1 = __int_as_float((int)(c1 >> 32));
        const float f2 = __int_as_float((int)(c2 >> 32));
        const float f3 = __int_as_float((int)(c3 >> 32));
        a0 = fmaf(f0, bl(w0.x), a0); a1 = fmaf(f0, bh(w0.x), a1);
        a2 = fmaf(f0, bl(w0.y), a2); a3 = fmaf(f0, bh(w0.y), a3);
        a4 = fmaf(f0, bl(w0.z), a4); a5 = fmaf(f0, bh(w0.z), a5);
        a6 = fmaf(f0, bl(w0.w), a6); a7 = fmaf(f0, bh(w0.w), a7);
        a0 = fmaf(f1, bl(w1.x), a0); a1 = fmaf(f1, bh(w1.x), a1);
        a2 = fmaf(f1, bl(w1.y), a2); a3 = fmaf(f1, bh(w1.y), a3);
        a4 = fmaf(f1, bl(w1.z), a4); a5 = fmaf(f1, bh(w1.z), a5);
        a6 = fmaf(f1, bl(w1.w), a6); a7 = fmaf(f1, bh(w1.w), a7);
        a0 = fmaf(f2, bl(w2.x), a0); a1 = fmaf(f2, bh(w2.x), a1);
        a2 = fmaf(f2, bl(w2.y), a2); a3 = fmaf(f2, bh(w2.y), a3);
        a4 = fmaf(f2, bl(w2.z), a4); a5 = fmaf(f2, bh(w2.z), a5);
        a6 = fmaf(f2, bl(w2.w), a6); a7 = fmaf(f2, bh(w2.w), a7);
        a0 = fmaf(f3, bl(w3.x), a0); a1 = fmaf(f3, bh(w3.x), a1);
        a2 = fmaf(f3, bl(w3.y), a2); a3 = fmaf(f3, bh(w3.y), a3);
        a4 = fmaf(f3, bl(w3.z), a4); a5 = fmaf(f3, bh(w3.z), a5);
        a6 = fmaf(f3, bl(w3.w), a6); a7 = fmaf(f3, bh(w3.w), a7);
    }
    for (; p + 8 <= e; p += 8) {
        const u64 c0 = ldnt8(&csr[p + q]);
        const u64 c1 = ldnt8(&csr[p + 4 + q]);
        const uint4 w0 = *(const uint4*)(h + (size_t)(int)c0 * 128 + col);
        const uint4 w1 = *(const uint4*)(h + (size_t)(int)c1 * 128 + col);
        const float f0 = __int_as_float((int)(c0 >> 32));
        const float f1 = __int_as_float((int)(c1 >> 32));
        a0 = fmaf(f0, bl(w0.x), a0); a1 = fmaf(f0, bh(w0.x), a1);
        a2 = fmaf(f0, bl(w0.y), a2); a3 = fmaf(f0, bh(w0.y), a3);
        a4 = fmaf(f0, bl(w0.z), a4); a5 = fmaf(f0, bh(w0.z), a5);
        a6 = fmaf(f0, bl(w0.w), a6); a7 = fmaf(f0, bh(w0.w), a7);
        a0 = fmaf(f1, bl(w1.x), a0); a1 = fmaf(f1, bh(w1.x), a1);
        a2 = fmaf(f1, bl(w1.y), a2); a3 = fmaf(f1, bh(w1.y), a3);
        a4 = fmaf(f1, bl(w1.z), a4); a5 = fmaf(f1, bh(w1.z), a5);
        a6 = fmaf(f1, bl(w1.w), a6); a7 = fmaf(f1, bh(w1.w), a7);
    }
    {
        const int i0 = p + q, i1 = p + 4 + q;
        if (i0 < e) {
            const u64 c = ldnt8(&csr[i0]);
            const uint4 w = *(const uint4*)(h + (size_t)(int)c * 128 + col);
            const float f = __int_as_float((int)(c >> 32));
            a0 = fmaf(f, bl(w.x), a0); a1 = fmaf(f, bh(w.x), a1);
            a2 = fmaf(f, bl(w.y), a2); a3 = fmaf(f, bh(w.y), a3);
            a4 = fmaf(f, bl(w.z), a4); a5 = fmaf(f, bh(w.z), a5);
            a6 = fmaf(f, bl(w.w), a6); a7 = fmaf(f, bh(w.w), a7);
        }
        if (i1 < e) {
            const u64 c = ldnt8(&csr[i1]);
            const uint4 w = *(const uint4*)(h + (size_t)(int)c * 128 + col);
            const float f = __int_as_float((int)(c >> 32));
            a0 = fmaf(f, bl(w.x), a0); a1 = fmaf(f, bh(w.x), a1);
            a2 = fmaf(f, bl(w.y), a2); a3 = fmaf(f, bh(w.y), a3);
            a4 = fmaf(f, bl(w.z), a4); a5 = fmaf(f, bh(w.z), a5);
            a6 = fmaf(f, bl(w.w), a6); a7 = fmaf(f, bh(w.w), a7);
        }
    }
    a0 += __shfl_xor(a0, 16); a1 += __shfl_xor(a1, 16);
    a2 += __shfl_xor(a2, 16); a3 += __shfl_xor(a3, 16);
    a4 += __shfl_xor(a4, 16); a5 += __shfl_xor(a5, 16);
    a6 += __shfl_xor(a6, 16); a7 += __shfl_xor(a7, 16);
    a0 += __shfl_xor(a0, 32); a1 += __shfl_xor(a1, 32);
    a2 += __shfl_xor(a2, 32); a3 += __shfl_xor(a3, 32);
    a4 += __shfl_xor(a4, 32); a5 += __shfl_xor(a5, 32);
    a6 += __shfl_xor(a6, 32); a7 += __shfl_xor(a7, 32);
    if (lane < 16) {
        const float nn = inorm[node];
        u16x8 r = {bfrn(a0 * nn), bfrn(a1 * nn), bfrn(a2 * nn), bfrn(a3 * nn),
                   bfrn(a4 * nn), bfrn(a5 * nn), bfrn(a6 * nn), bfrn(a7 * nn)};
        *(u16x8*)(out + (size_t)node * 128 + col) = r;
    }
}

// one wave per node, width 64 bf16: eighth-wave per edge; fused bias; fp32 out
__global__ void __launch_bounds__(256)
k_agg64b(const u16* __restrict__ h, const int* __restrict__ row,
         const int2* __restrict__ csr, const float* __restrict__ inorm,
         const float* __restrict__ bias, float* __restrict__ out, int N) {
    const int node = (int)((blockIdx.x * blockDim.x + threadIdx.x) >> 6);
    if (node >= N) return;
    const int lane = threadIdx.x & 63;
    const int oc = lane >> 3;
    const int col = (lane & 7) * 8;
    int p = row[node];
    const int e = row[node + 1];
    float a0 = 0, a1 = 0, a2 = 0, a3 = 0, a4 = 0, a5 = 0, a6 = 0, a7 = 0;
    for (; p + 16 <= e; p += 16) {
        const u64 c0 = ldnt8(&csr[p + oc]);
        const u64 c1 = ldnt8(&csr[p + 8 + oc]);
        const uint4 w0 = *(const uint4*)(h + (size_t)(int)c0 * 64 + col);
        const uint4 w1 = *(const uint4*)(h + (size_t)(int)c1 * 64 + col);
        const float f0 = __int_as_float((int)(c0 >> 32));
        const float f1 = __int_as_float((int)(c1 >> 32));
        a0 = fmaf(f0, bl(w0.x), a0); a1 = fmaf(f0, bh(w0.x), a1);
        a2 = fmaf(f0, bl(w0.y), a2); a3 = fmaf(f0, bh(w0.y), a3);
        a4 = fmaf(f0, bl(w0.z), a4); a5 = fmaf(f0, bh(w0.z), a5);
        a6 = fmaf(f0, bl(w0.w), a6); a7 = fmaf(f0, bh(w0.w), a7);
        a0 = fmaf(f1, bl(w1.x), a0); a1 = fmaf(f1, bh(w1.x), a1);
        a2 = fmaf(f1, bl(w1.y), a2); a3 = fmaf(f1, bh(w1.y), a3);
        a4 = fmaf(f1, bl(w1.z), a4); a5 = fmaf(f1, bh(w1.z), a5);
        a6 = fmaf(f1, bl(w1.w), a6); a7 = fmaf(f1, bh(w1.w), a7);
    }
    {
        const int i0 = p + oc, i1 = p + 8 + oc;
        if (i0 < e) {
            const u64 c = ldnt8(&csr[i0]);
            const uint4 w = *(const uint4*)(h + (size_t)(int)c * 64 + col);
            const float f = __int_as_float((int)(c >> 32));
            a0 = fmaf(f, bl(w.x), a0); a1 = fmaf(f, bh(w.x), a1);
            a2 = fmaf(f, bl(w.y), a2); a3 = fmaf(f, bh(w.y), a3);
            a4 = fmaf(f, bl(w.z), a4); a5 = fmaf(f, bh(w.z), a5);
            a6 = fmaf(f, bl(w.w), a6); a7 = fmaf(f, bh(w.w), a7);
        }
        if (i1 < e) {
            const u64 c = ldnt8(&csr[i1]);
            const uint4 w = *(const uint4*)(h + (size_t)(int)c * 64 + col);
            const float f = __int_as_float((int)(c >> 32));
            a0 = fmaf(f, bl(w.x), a0); a1 = fmaf(f, bh(w.x), a1);
            a2 = fmaf(f, bl(w.y), a2); a3 = fmaf(f, bh(w.y), a3);
            a4 = fmaf(f, bl(w.z), a4); a5 = fmaf(f, bh(w.z), a5);
            a6 = fmaf(f, bl(w.w), a6); a7 = fmaf(f, bh(w.w), a7);
        }
    }
    a0 += __shfl_xor(a0, 8);  a1 += __shfl_xor(a1, 8);
    a2 += __shfl_xor(a2, 8);  a3 += __shfl_xor(a3, 8);
    a4 += __shfl_xor(a4, 8);  a5 += __shfl_xor(a5, 8);
    a6 += __shfl_xor(a6, 8);  a7 += __shfl_xor(a7, 8);
    a0 += __shfl_xor(a0, 16); a1 += __shfl_xor(a1, 16);
    a2 += __shfl_xor(a2, 16); a3 += __shfl_xor(a3, 16);
    a4 += __shfl_xor(a4, 16); a5 += __shfl_xor(a5, 16);
    a6 += __shfl_xor(a6, 16); a7 += __shfl_xor(a7, 16);
    a0 += __shfl_xor(a0, 32); a1 += __shfl_xor(a1, 32);
    a2 += __shfl_xor(a2, 32); a3 += __shfl_xor(a3, 32);
    a4 += __shfl_xor(a4, 32); a5 += __shfl_xor(a5, 32);
    a6 += __shfl_xor(a6, 32); a7 += __shfl_xor(a7, 32);
    if (lane < 8) {
        const float nn = inorm[node];
        const f4 b0 = *(const f4*)(bias + col);
        const f4 b1 = *(const f4*)(bias + col + 4);
        f4 r0 = {a0 * nn + b0.x, a1 * nn + b0.y, a2 * nn + b0.z, a3 * nn + b0.w};
        f4 r1 = {a4 * nn + b1.x, a5 * nn + b1.y, a6 * nn + b1.z, a7 * nn + b1.w};
        *(f4*)(out + (size_t)node * 64 + col) = r0;
        *(f4*)(out + (size_t)node * 64 + col + 4) = r1;
    }
}

// MFMA GEMM: C[N x COLS] = A[N x 128] @ W[128 x COLS] (+bias,+relu), bf16 io.
template <int COLS, bool RELU, bool BIAS>
__global__ void __launch_bounds__(256)
k_mgemm(const u16* __restrict__ A, const u16* __restrict__ Wt,
        const float* __restrict__ bias, u16* __restrict__ C, int N) {
    __shared__ u16 Wl[COLS][136];
    const int t = threadIdx.x;
    const int lane = t & 63;
    const int wave = t >> 6;
    #pragma unroll
    for (int i = 0; i < COLS / 16; ++i) {
        const int elem = (i * 256 + t) * 8;
        const int r = elem >> 7, c0 = elem & 127;
        *(short8*)&Wl[r][c0] = *(const short8*)(Wt + elem);
    }
    const int row0 = blockIdx.x * 64 + wave * 16;
    const int arow = min(row0 + (lane & 15), N - 1);
    const int koff = (lane >> 4) * 8;
    short8 a[4];
    #pragma unroll
    for (int kk = 0; kk < 4; ++kk)
        a[kk] = *(const short8*)(A + (size_t)arow * 128 + kk * 32 + koff);
    __syncthreads();

    f4 acc[COLS / 16];
    #pragma unroll
    for (int ct = 0; ct < COLS / 16; ++ct) acc[ct] = (f4){0.f, 0.f, 0.f, 0.f};

    #pragma unroll
    for (int ct = 0; ct < COLS / 16; ++ct) {
        #pragma unroll
        for (int kk = 0; kk < 4; ++kk) {
            const short8 b = *(const short8*)&Wl[ct * 16 + (lane & 15)][kk * 32 + koff];
            acc[ct] = __builtin_amdgcn_mfma_f32_16x16x32_bf16(a[kk], b, acc[ct], 0, 0, 0);
        }
    }

    #pragma unroll
    for (int ct = 0; ct < COLS / 16; ++ct) {
        const int c = ct * 16 + (lane & 15);
        const float bb = BIAS ? bias[c] : 0.f;
        #pragma unroll
        for (int r = 0; r < 4; ++r) {
            const int gr = row0 + (lane >> 4) * 4 + r;
            if (gr < N) {
                float v = acc[ct][r] + bb;
                if (RELU) v = v > 0.f ? v : 0.f;
                C[(size_t)gr * COLS + c] = bfrn(v);
            }
        }
    }
}

extern "C" void kernel_launch(void* const* d_in, const int* in_sizes, int n_in,
                              void* d_out, int out_size, void* d_ws, size_t ws_size,
                              hipStream_t stream) {
    const float* feat = (const float*)d_in[0];
    const int*   src  = (const int*)d_in[1];
    const int*   dst  = (const int*)d_in[2];
    const float* ew   = (const float*)d_in[3];
    const float* W0   = (const float*)d_in[4];
    const float* b0   = (const float*)d_in[5];
    const float* W1   = (const float*)d_in[6];
    const float* b1   = (const float*)d_in[7];
    const float* W2   = (const float*)d_in[8];
    const float* b2   = (const float*)d_in[9];
    float* out = (float*)d_out;

    const int N = in_sizes[0] / 128;
    const int E = in_sizes[1];
    const int NB = (N + 255) / 256;
    const int B1 = (E + EPB - 1) / EPB;
    const int n8 = N * 16;                 // N*128/8 bf16x8 groups

    uint8_t* wp = (uint8_t*)d_ws;
    auto alloc = [&](size_t bytes) {
        uint8_t* r = wp;
        wp += (bytes + 511) & ~(size_t)511;
        return r;
    };
    u16*   featb = (u16*)alloc((size_t)N * 128 * 2);  // layer-0 input / layer-1 GEMM output
    u16*   Xb    = (u16*)alloc((size_t)N * 128 * 2);  // aliases prep hists
    u16*   Tb    = (u16*)alloc((size_t)N * 128 * 2);  // agg output (ping)
    u8*    scr   = (u8*)alloc((size_t)E * 10 + 65536); // tsw+tsrc; later Gb
    int2*  csr   = (int2*)alloc((size_t)E * 8);
    int*   row   = (int*)alloc((size_t)(N + 1) * 4);
    float* onorm = (float*)alloc((size_t)N * 4);
    float* inorm = (float*)alloc((size_t)N * 4);
    u16*   Wt0   = (u16*)alloc(128 * 128 * 2);
    u16*   Wt1   = (u16*)alloc(128 * 128 * 2);
    u16*   Wt2   = (u16*)alloc(128 * 64 * 2);

    // prep-phase aliases inside Xb (dead before Xb first written by layer-0 GEMM)
    uint8_t* xp = (uint8_t*)Xb;
    auto xalloc = [&](size_t bytes) {
        uint8_t* r = xp;
        xp += (bytes + 511) & ~(size_t)511;
        return r;
    };
    int* bh_d   = (int*)xalloc((size_t)B1 * NB * 4);
    int* bh_s   = (int*)xalloc((size_t)B1 * NB * 4);
    int* cb_d   = (int*)xalloc((size_t)NB * 4);
    int* cb_s   = (int*)xalloc((size_t)NB * 4);
    int* bktb_d = (int*)xalloc((size_t)NB * 4);
    int* bktb_s = (int*)xalloc((size_t)NB * 4);

    // prep tables + layer-2 G inside scr
    uint8_t* yp = scr;
    auto yalloc = [&](size_t bytes) {
        uint8_t* r = yp;
        yp += (bytes + 511) & ~(size_t)511;
        return r;
    };
    int2* tsw  = (int2*)yalloc((size_t)E * 8);
    u8*   tsrc = (u8*)yalloc((size_t)E);
    u16*  Gb   = (u16*)scr;   // written by layer-2 GEMM after prep complete

    // ---- fused conversions + CSR build (LDS atomics only) ----
    const int nbcvt = (n8 + 255) / 256;
    k_prep0<<<B1 + nbcvt + 160, 256, 0, stream>>>(
        src, dst, bh_s, bh_d, feat, featb, n8,
        W0, W1, W2, Wt0, Wt1, Wt2, NB, B1, E);
    k_p2<<<dim3((NB + 15) / 16, 2), 512, 0, stream>>>(bh_d, bh_s, cb_d, cb_s, NB, B1);
    k_p2b<<<1, 512, 0, stream>>>(cb_d, cb_s, bktb_d, bktb_s, row, NB, N, E);
    k_p3<<<B1, 256, 0, stream>>>(src, dst, ew, bh_s, bh_d, bktb_s, bktb_d,
                                 tsw, tsrc, NB, E);
    k_p4s<<<NB, 256, 0, stream>>>(tsrc, bktb_s, cb_s, onorm, NB, N);
    k_p4d<<<NB, 256, 0, stream>>>(tsw, bktb_d, cb_d, onorm, row, inorm, csr, NB, N);

    // ---- 3 GraphConv layers ----
    const int ab = (N + 3) / 4;
    const int gb = (N + 63) / 64;

    // layer 0: agg(featb) -> Tb ; Xb = relu(Tb@W0 + b0)
    k_agg128b<<<ab, 256, 0, stream>>>(featb, row, csr, inorm, Tb, N);
    k_mgemm<128, true, true><<<gb, 256, 0, stream>>>(Tb, Wt0, b0, Xb, N);
    // layer 1: agg(Xb) -> Tb ; featb = relu(Tb@W1 + b1)
    k_agg128b<<<ab, 256, 0, stream>>>(Xb, row, csr, inorm, Tb, N);
    k_mgemm<128, true, true><<<gb, 256, 0, stream>>>(Tb, Wt1, b1, featb, N);
    // layer 2: Gb = featb@W2 ; out = inorm .* agg(Gb) + b2
    k_mgemm<64, false, false><<<gb, 256, 0, stream>>>(featb, Wt2, nullptr, Gb, N);
    k_agg64b<<<ab, 256, 0, stream>>>(Gb, row, csr, inorm, b2, out, N);
}

// Round 10
// 303.195 us; speedup vs baseline: 1.1642x; 1.0267x over previous
//
#include <hip/hip_runtime.h>
#include <cstddef>
#include <cstdint>

typedef float f4 __attribute__((ext_vector_type(4)));
typedef unsigned long long u64;
typedef unsigned short u16;
typedef unsigned char u8;
typedef unsigned short u16x8 __attribute__((ext_vector_type(8)));
typedef short short8 __attribute__((ext_vector_type(8)));

__device__ __forceinline__ u64 ldnt8(const void* p) {
    return __builtin_nontemporal_load((const u64*)(p));
}
// bf16 round-to-nearest-even
__device__ __forceinline__ u16 bfrn(float f) {
    unsigned u = __float_as_uint(f);
    return (u16)((u + 0x7FFFu + ((u >> 16) & 1u)) >> 16);
}
__device__ __forceinline__ float bl(unsigned w) { return __uint_as_float(w << 16); }
__device__ __forceinline__ float bh(unsigned w) { return __uint_as_float(w & 0xFFFF0000u); }

// ---------------------------------------------------------------------------
// GraphConv x3 (DGL norm='both', per-edge weight)
// onorm is FOLDED INTO THE STORED OPERAND (DGL's own h*out_norm formulation):
//   featb = bf16(onorm .* feat);  layer-0/1 GEMM epilogue scales by onorm[row]
//   => csr coef = ew exactly; no per-edge onorm gather in the sort.
// CSR build: two-level counting sort (LDS atomics only).
//   prep0: fused {W->Wt cvt | per-block coarse histograms}
//   p2/p2b: scans;  p3: rank-recompute + scatter tsw={dstlo<<24|src, ew}, tsrc
//   p4 (y=0): per-bucket outdeg -> onorm + feat scale/cvt   [independent]
//   p4 (y=1): per-bucket fine sort -> row/inorm/csr          [independent]
// Layers: split agg (bf16 gather, fp32 acc) + MFMA GEMM (proven).
// ---------------------------------------------------------------------------

#define EPB 4096

// fused: blocks [0,B1) = coarse histograms; [B1,B1+160) = W cvt
__global__ void __launch_bounds__(256)
k_prep0(const int* __restrict__ src, const int* __restrict__ dst,
        int* __restrict__ bh_s, int* __restrict__ bh_d,
        const float* __restrict__ W0, const float* __restrict__ W1,
        const float* __restrict__ W2, u16* __restrict__ Wt0,
        u16* __restrict__ Wt1, u16* __restrict__ Wt2,
        int NB, int B1, int E) {
    const int bid = blockIdx.x, t = threadIdx.x;
    if (bid < B1) {
        __shared__ int hs[512], hd[512];
        for (int i = t; i < 512; i += 256) { hs[i] = 0; hd[i] = 0; }
        __syncthreads();
        const int e0 = bid * EPB;
        #pragma unroll
        for (int j = 0; j < 4; ++j) {
            const int e = e0 + j * 1024 + t * 4;
            if (e + 4 <= E) {
                const int4 d = *(const int4*)&dst[e];
                const int4 s = *(const int4*)&src[e];
                atomicAdd(&hd[d.x >> 8], 1);
                atomicAdd(&hd[d.y >> 8], 1);
                atomicAdd(&hd[d.z >> 8], 1);
                atomicAdd(&hd[d.w >> 8], 1);
                atomicAdd(&hs[s.x >> 8], 1);
                atomicAdd(&hs[s.y >> 8], 1);
                atomicAdd(&hs[s.z >> 8], 1);
                atomicAdd(&hs[s.w >> 8], 1);
            } else {
                for (int k = e; k < E && k < e + 4; ++k) {
                    atomicAdd(&hd[dst[k] >> 8], 1);
                    atomicAdd(&hs[src[k] >> 8], 1);
                }
            }
        }
        __syncthreads();
        for (int i = t; i < NB; i += 256) {
            bh_d[bid * NB + i] = hd[i];
            bh_s[bid * NB + i] = hs[i];
        }
    } else {
        const int i = (bid - B1) * 256 + t;
        if (i < 16384) {
            const int k = i >> 7, c = i & 127;
            Wt0[c * 128 + k] = bfrn(W0[i]);
        } else if (i < 32768) {
            const int j = i - 16384, k = j >> 7, c = j & 127;
            Wt1[c * 128 + k] = bfrn(W1[j]);
        } else if (i < 40960) {
            const int j = i - 32768, k = j >> 6, c = j & 63;
            Wt2[c * 128 + k] = bfrn(W2[j]);
        }
    }
}

// P2: per bucket exclusive scan over blocks; coalesced via 512x16 LDS tile.
__global__ void __launch_bounds__(512)
k_p2(int* __restrict__ bh_d, int* __restrict__ bh_s,
     int* __restrict__ cb_d, int* __restrict__ cb_s, int NB, int B1) {
    __shared__ int tile[512][17];
    __shared__ int tot[16];
    const int t = threadIdx.x, lane = t & 63, wave = t >> 6;
    int* bh = blockIdx.y ? bh_s : bh_d;
    int* cb = blockIdx.y ? cb_s : cb_d;
    const int B0 = blockIdx.x * 16;
    #pragma unroll
    for (int j = 0; j < 16; ++j) {
        const int idx = j * 512 + t;
        const int row = idx >> 4, col = idx & 15;
        int v = 0;
        if (row < B1 && B0 + col < NB) v = bh[row * NB + B0 + col];
        tile[row][col] = v;
    }
    __syncthreads();
    #pragma unroll
    for (int cc = 0; cc < 2; ++cc) {
        const int col = wave * 2 + cc;
        int carry = 0;
        #pragma unroll
        for (int ch = 0; ch < 8; ++ch) {
            const int v = tile[ch * 64 + lane][col];
            int s = v;
            #pragma unroll
            for (int d = 1; d < 64; d <<= 1) {
                const int u = __shfl_up(s, d);
                if (lane >= d) s += u;
            }
            tile[ch * 64 + lane][col] = s - v + carry;
            carry += __shfl(s, 63);
        }
        if (lane == 0) tot[col] = carry;
    }
    __syncthreads();
    #pragma unroll
    for (int j = 0; j < 16; ++j) {
        const int idx = j * 512 + t;
        const int row = idx >> 4, col = idx & 15;
        if (row < B1 && B0 + col < NB) bh[row * NB + B0 + col] = tile[row][col];
    }
    if (t < 16 && B0 + t < NB) cb[B0 + t] = tot[t];
}

__global__ void __launch_bounds__(512)
k_p2b(const int* __restrict__ cb_d, const int* __restrict__ cb_s,
      int* __restrict__ bktb_d, int* __restrict__ bktb_s,
      int* __restrict__ row, int NB, int N, int E) {
    __shared__ int s[512];
    const int t = threadIdx.x;
    int v = (t < NB) ? cb_d[t] : 0;
    s[t] = v;
    __syncthreads();
    for (int off = 1; off < 512; off <<= 1) {
        const int x = (t >= off) ? s[t - off] : 0;
        __syncthreads();
        s[t] += x;
        __syncthreads();
    }
    if (t < NB) bktb_d[t] = s[t] - v;
    __syncthreads();
    v = (t < NB) ? cb_s[t] : 0;
    s[t] = v;
    __syncthreads();
    for (int off = 1; off < 512; off <<= 1) {
        const int x = (t >= off) ? s[t - off] : 0;
        __syncthreads();
        s[t] += x;
        __syncthreads();
    }
    if (t < NB) bktb_s[t] = s[t] - v;
    if (t == 0) row[N] = E;
}

__global__ void __launch_bounds__(256)
k_p3(const int* __restrict__ src, const int* __restrict__ dst,
     const float* __restrict__ ew,
     const int* __restrict__ bh_s, const int* __restrict__ bh_d,
     const int* __restrict__ bktb_s, const int* __restrict__ bktb_d,
     int2* __restrict__ tsw, u8* __restrict__ tsrc, int NB, int E) {
    __shared__ int hs[512], hd[512], base_s[512], base_d[512];
    const int t = threadIdx.x, b = blockIdx.x;
    for (int i = t; i < 512; i += 256) {
        hs[i] = 0; hd[i] = 0;
        if (i < NB) {
            base_d[i] = bktb_d[i] + bh_d[b * NB + i];
            base_s[i] = bktb_s[i] + bh_s[b * NB + i];
        }
    }
    __syncthreads();
    const int e0 = b * EPB;
    #pragma unroll
    for (int j = 0; j < 4; ++j) {
        const int e = e0 + j * 1024 + t * 4;
        if (e + 4 <= E) {
            const int4 d = *(const int4*)&dst[e];
            const int4 s = *(const int4*)&src[e];
            const f4   w = *(const f4*)&ew[e];
            const int dd[4] = {d.x, d.y, d.z, d.w};
            const int ss[4] = {s.x, s.y, s.z, s.w};
            const float ww[4] = {w.x, w.y, w.z, w.w};
            #pragma unroll
            for (int k = 0; k < 4; ++k) {
                const int Bd = dd[k] >> 8;
                const int rd = atomicAdd(&hd[Bd], 1);
                tsw[base_d[Bd] + rd] = make_int2(ss[k] | ((dd[k] & 255) << 24),
                                                 __float_as_int(ww[k]));
                const int Bs = ss[k] >> 8;
                const int rs = atomicAdd(&hs[Bs], 1);
                tsrc[base_s[Bs] + rs] = (u8)(ss[k] & 255);
            }
        } else {
            for (int k = e; k < E && k < e + 4; ++k) {
                const int dv = dst[k], sv = src[k];
                const int Bd = dv >> 8;
                const int rd = atomicAdd(&hd[Bd], 1);
                tsw[base_d[Bd] + rd] = make_int2(sv | ((dv & 255) << 24),
                                                 __float_as_int(ew[k]));
                const int Bs = sv >> 8;
                const int rs = atomicAdd(&hs[Bs], 1);
                tsrc[base_s[Bs] + rs] = (u8)(sv & 255);
            }
        }
    }
}

// P4 fused: y=0 -> outdeg/onorm + feat scale/cvt; y=1 -> fine sort -> csr
__global__ void __launch_bounds__(256)
k_p4(const u8* __restrict__ tsrc, const int2* __restrict__ tsw,
     const int* __restrict__ bktb_s, const int* __restrict__ cb_s,
     const int* __restrict__ bktb_d, const int* __restrict__ cb_d,
     const float* __restrict__ feat, u16* __restrict__ featb,
     float* __restrict__ onorm, int* __restrict__ row,
     float* __restrict__ inorm, int2* __restrict__ csr, int NB, int N) {
    const int B = blockIdx.x, t = threadIdx.x;
    if (blockIdx.y == 0) {
        // outdeg -> onorm; then featb = bf16(onorm .* feat) for this bucket
        __shared__ int cnt[256];
        __shared__ float nrm[256];
        cnt[t] = 0;
        __syncthreads();
        const int base = bktb_s[B], cb = cb_s[B];
        for (int i = t; i < cb; i += 256) atomicAdd(&cnt[tsrc[base + i]], 1);
        __syncthreads();
        const int n = (B << 8) + t;
        const int c = cnt[t];
        const float o = rsqrtf((float)(c < 1 ? 1 : c));
        nrm[t] = o;
        if (n < N) onorm[n] = o;
        __syncthreads();
        const int n0 = B << 8;
        for (int idx = t; idx < 256 * 16; idx += 256) {
            const int node = idx >> 4, g = idx & 15;
            const int gn = n0 + node;
            if (gn < N) {
                const float o2 = nrm[node];
                const f4 v0 = *(const f4*)(feat + (size_t)gn * 128 + g * 8);
                const f4 v1 = *(const f4*)(feat + (size_t)gn * 128 + g * 8 + 4);
                u16x8 r = {bfrn(v0.x * o2), bfrn(v0.y * o2),
                           bfrn(v0.z * o2), bfrn(v0.w * o2),
                           bfrn(v1.x * o2), bfrn(v1.y * o2),
                           bfrn(v1.z * o2), bfrn(v1.w * o2)};
                *(u16x8*)(featb + (size_t)gn * 128 + g * 8) = r;
            }
        }
    } else {
        // fine sort: count -> scan -> row/inorm -> rank-scatter csr = (src, ew)
        __shared__ int cnt[256], cnt2[256], lrow[256], sc[256];
        cnt[t] = 0; cnt2[t] = 0;
        __syncthreads();
        const int base = bktb_d[B], cb = cb_d[B];
        for (int i = t; i < cb; i += 256)
            atomicAdd(&cnt[((unsigned)tsw[base + i].x) >> 24], 1);
        __syncthreads();
        const int v = cnt[t];
        sc[t] = v;
        __syncthreads();
        for (int off = 1; off < 256; off <<= 1) {
            const int x = (t >= off) ? sc[t - off] : 0;
            __syncthreads();
            sc[t] += x;
            __syncthreads();
        }
        const int excl = sc[t] - v;
        lrow[t] = excl;
        const int n = (B << 8) + t;
        if (n < N) {
            row[n] = base + excl;
            inorm[n] = rsqrtf((float)(v < 1 ? 1 : v));
        }
        __syncthreads();
        for (int i = t; i < cb; i += 256) {
            const int2 sw = tsw[base + i];
            const int d = ((unsigned)sw.x) >> 24;
            const int r = atomicAdd(&cnt2[d], 1);
            csr[base + lrow[d] + r] = make_int2(sw.x & 0xFFFFFF, sw.y);
        }
    }
}

// one wave per node, width 128 bf16: quarter-wave per edge, 16 edges/iter
__global__ void __launch_bounds__(256)
k_agg128b(const u16* __restrict__ h, const int* __restrict__ row,
          const int2* __restrict__ csr, const float* __restrict__ inorm,
          u16* __restrict__ out, int N) {
    const int node = (int)((blockIdx.x * blockDim.x + threadIdx.x) >> 6);
    if (node >= N) return;
    const int lane = threadIdx.x & 63;
    const int q = lane >> 4;
    const int col = (lane & 15) * 8;
    int p = row[node];
    const int e = row[node + 1];
    float a0 = 0, a1 = 0, a2 = 0, a3 = 0, a4 = 0, a5 = 0, a6 = 0, a7 = 0;
    for (; p + 16 <= e; p += 16) {
        const u64 c0 = ldnt8(&csr[p + q]);
        const u64 c1 = ldnt8(&csr[p + 4 + q]);
        const u64 c2 = ldnt8(&csr[p + 8 + q]);
        const u64 c3 = ldnt8(&csr[p + 12 + q]);
        const uint4 w0 = *(const uint4*)(h + (size_t)(int)c0 * 128 + col);
        const uint4 w1 = *(const uint4*)(h + (size_t)(int)c1 * 128 + col);
        const uint4 w2 = *(const uint4*)(h + (size_t)(int)c2 * 128 + col);
        const uint4 w3 = *(const uint4*)(h + (size_t)(int)c3 * 128 + col);
        const float f0 = __int_as_float((int)(c0 >> 32));
        const float f1 = __int_as_float((int)(c1 >> 32));
        const float f2 = __int_as_float((int)(c2 >> 32));
        const float f3 = __int_as_float((int)(c3 >> 32));
        a0 = fmaf(f0, bl(w0.x), a0); a1 = fmaf(f0, bh(w0.x), a1);
        a2 = fmaf(f0, bl(w0.y), a2); a3 = fmaf(f0, bh(w0.y), a3);
        a4 = fmaf(f0, bl(w0.z), a4); a5 = fmaf(f0, bh(w0.z), a5);
        a6 = fmaf(f0, bl(w0.w), a6); a7 = fmaf(f0, bh(w0.w), a7);
        a0 = fmaf(f1, bl(w1.x), a0); a1 = fmaf(f1, bh(w1.x), a1);
        a2 = fmaf(f1, bl(w1.y), a2); a3 = fmaf(f1, bh(w1.y), a3);
        a4 = fmaf(f1, bl(w1.z), a4); a5 = fmaf(f1, bh(w1.z), a5);
        a6 = fmaf(f1, bl(w1.w), a6); a7 = fmaf(f1, bh(w1.w), a7);
        a0 = fmaf(f2, bl(w2.x), a0); a1 = fmaf(f2, bh(w2.x), a1);
        a2 = fmaf(f2, bl(w2.y), a2); a3 = fmaf(f2, bh(w2.y), a3);
        a4 = fmaf(f2, bl(w2.z), a4); a5 = fmaf(f2, bh(w2.z), a5);
        a6 = fmaf(f2, bl(w2.w), a6); a7 = fmaf(f2, bh(w2.w), a7);
        a0 = fmaf(f3, bl(w3.x), a0); a1 = fmaf(f3, bh(w3.x), a1);
        a2 = fmaf(f3, bl(w3.y), a2); a3 = fmaf(f3, bh(w3.y), a3);
        a4 = fmaf(f3, bl(w3.z), a4); a5 = fmaf(f3, bh(w3.z), a5);
        a6 = fmaf(f3, bl(w3.w), a6); a7 = fmaf(f3, bh(w3.w), a7);
    }
    for (; p + 8 <= e; p += 8) {
        const u64 c0 = ldnt8(&csr[p + q]);
        const u64 c1 = ldnt8(&csr[p + 4 + q]);
        const uint4 w0 = *(const uint4*)(h + (size_t)(int)c0 * 128 + col);
        const uint4 w1 = *(const uint4*)(h + (size_t)(int)c1 * 128 + col);
        const float f0 = __int_as_float((int)(c0 >> 32));
        const float f1 = __int_as_float((int)(c1 >> 32));
        a0 = fmaf(f0, bl(w0.x), a0); a1 = fmaf(f0, bh(w0.x), a1);
        a2 = fmaf(f0, bl(w0.y), a2); a3 = fmaf(f0, bh(w0.y), a3);
        a4 = fmaf(f0, bl(w0.z), a4); a5 = fmaf(f0, bh(w0.z), a5);
        a6 = fmaf(f0, bl(w0.w), a6); a7 = fmaf(f0, bh(w0.w), a7);
        a0 = fmaf(f1, bl(w1.x), a0); a1 = fmaf(f1, bh(w1.x), a1);
        a2 = fmaf(f1, bl(w1.y), a2); a3 = fmaf(f1, bh(w1.y), a3);
        a4 = fmaf(f1, bl(w1.z), a4); a5 = fmaf(f1, bh(w1.z), a5);
        a6 = fmaf(f1, bl(w1.w), a6); a7 = fmaf(f1, bh(w1.w), a7);
    }
    {
        const int i0 = p + q, i1 = p + 4 + q;
        if (i0 < e) {
            const u64 c = ldnt8(&csr[i0]);
            const uint4 w = *(const uint4*)(h + (size_t)(int)c * 128 + col);
            const float f = __int_as_float((int)(c >> 32));
            a0 = fmaf(f, bl(w.x), a0); a1 = fmaf(f, bh(w.x), a1);
            a2 = fmaf(f, bl(w.y), a2); a3 = fmaf(f, bh(w.y), a3);
            a4 = fmaf(f, bl(w.z), a4); a5 = fmaf(f, bh(w.z), a5);
            a6 = fmaf(f, bl(w.w), a6); a7 = fmaf(f, bh(w.w), a7);
        }
        if (i1 < e) {
            const u64 c = ldnt8(&csr[i1]);
            const uint4 w = *(const uint4*)(h + (size_t)(int)c * 128 + col);
            const float f = __int_as_float((int)(c >> 32));
            a0 = fmaf(f, bl(w.x), a0); a1 = fmaf(f, bh(w.x), a1);
            a2 = fmaf(f, bl(w.y), a2); a3 = fmaf(f, bh(w.y), a3);
            a4 = fmaf(f, bl(w.z), a4); a5 = fmaf(f, bh(w.z), a5);
            a6 = fmaf(f, bl(w.w), a6); a7 = fmaf(f, bh(w.w), a7);
        }
    }
    a0 += __shfl_xor(a0, 16); a1 += __shfl_xor(a1, 16);
    a2 += __shfl_xor(a2, 16); a3 += __shfl_xor(a3, 16);
    a4 += __shfl_xor(a4, 16); a5 += __shfl_xor(a5, 16);
    a6 += __shfl_xor(a6, 16); a7 += __shfl_xor(a7, 16);
    a0 += __shfl_xor(a0, 32); a1 += __shfl_xor(a1, 32);
    a2 += __shfl_xor(a2, 32); a3 += __shfl_xor(a3, 32);
    a4 += __shfl_xor(a4, 32); a5 += __shfl_xor(a5, 32);
    a6 += __shfl_xor(a6, 32); a7 += __shfl_xor(a7, 32);
    if (lane < 16) {
        const float nn = inorm[node];
        u16x8 r = {bfrn(a0 * nn), bfrn(a1 * nn), bfrn(a2 * nn), bfrn(a3 * nn),
                   bfrn(a4 * nn), bfrn(a5 * nn), bfrn(a6 * nn), bfrn(a7 * nn)};
        *(u16x8*)(out + (size_t)node * 128 + col) = r;
    }
}

// one wave per node, width 64 bf16: eighth-wave per edge; fused bias; fp32 out
__global__ void __launch_bounds__(256)
k_agg64b(const u16* __restrict__ h, const int* __restrict__ row,
         const int2* __restrict__ csr, const float* __restrict__ inorm,
         const float* __restrict__ bias, float* __restrict__ out, int N) {
    const int node = (int)((blockIdx.x * blockDim.x + threadIdx.x) >> 6);
    if (node >= N) return;
    const int lane = threadIdx.x & 63;
    const int oc = lane >> 3;
    const int col = (lane & 7) * 8;
    int p = row[node];
    const int e = row[node + 1];
    float a0 = 0, a1 = 0, a2 = 0, a3 = 0, a4 = 0, a5 = 0, a6 = 0, a7 = 0;
    for (; p + 16 <= e; p += 16) {
        const u64 c0 = ldnt8(&csr[p + oc]);
        const u64 c1 = ldnt8(&csr[p + 8 + oc]);
        const uint4 w0 = *(const uint4*)(h + (size_t)(int)c0 * 64 + col);
        const uint4 w1 = *(const uint4*)(h + (size_t)(int)c1 * 64 + col);
        const float f0 = __int_as_float((int)(c0 >> 32));
        const float f1 = __int_as_float((int)(c1 >> 32));
        a0 = fmaf(f0, bl(w0.x), a0); a1 = fmaf(f0, bh(w0.x), a1);
        a2 = fmaf(f0, bl(w0.y), a2); a3 = fmaf(f0, bh(w0.y), a3);
        a4 = fmaf(f0, bl(w0.z), a4); a5 = fmaf(f0, bh(w0.z), a5);
        a6 = fmaf(f0, bl(w0.w), a6); a7 = fmaf(f0, bh(w0.w), a7);
        a0 = fmaf(f1, bl(w1.x), a0); a1 = fmaf(f1, bh(w1.x), a1);
        a2 = fmaf(f1, bl(w1.y), a2); a3 = fmaf(f1, bh(w1.y), a3);
        a4 = fmaf(f1, bl(w1.z), a4); a5 = fmaf(f1, bh(w1.z), a5);
        a6 = fmaf(f1, bl(w1.w), a6); a7 = fmaf(f1, bh(w1.w), a7);
    }
    {
        const int i0 = p + oc, i1 = p + 8 + oc;
        if (i0 < e) {
            const u64 c = ldnt8(&csr[i0]);
            const uint4 w = *(const uint4*)(h + (size_t)(int)c * 64 + col);
            const float f = __int_as_float((int)(c >> 32));
            a0 = fmaf(f, bl(w.x), a0); a1 = fmaf(f, bh(w.x), a1);
            a2 = fmaf(f, bl(w.y), a2); a3 = fmaf(f, bh(w.y), a3);
            a4 = fmaf(f, bl(w.z), a4); a5 = fmaf(f, bh(w.z), a5);
            a6 = fmaf(f, bl(w.w), a6); a7 = fmaf(f, bh(w.w), a7);
        }
        if (i1 < e) {
            const u64 c = ldnt8(&csr[i1]);
            const uint4 w = *(const uint4*)(h + (size_t)(int)c * 64 + col);
            const float f = __int_as_float((int)(c >> 32));
            a0 = fmaf(f, bl(w.x), a0); a1 = fmaf(f, bh(w.x), a1);
            a2 = fmaf(f, bl(w.y), a2); a3 = fmaf(f, bh(w.y), a3);
            a4 = fmaf(f, bl(w.z), a4); a5 = fmaf(f, bh(w.z), a5);
            a6 = fmaf(f, bl(w.w), a6); a7 = fmaf(f, bh(w.w), a7);
        }
    }
    a0 += __shfl_xor(a0, 8);  a1 += __shfl_xor(a1, 8);
    a2 += __shfl_xor(a2, 8);  a3 += __shfl_xor(a3, 8);
    a4 += __shfl_xor(a4, 8);  a5 += __shfl_xor(a5, 8);
    a6 += __shfl_xor(a6, 8);  a7 += __shfl_xor(a7, 8);
    a0 += __shfl_xor(a0, 16); a1 += __shfl_xor(a1, 16);
    a2 += __shfl_xor(a2, 16); a3 += __shfl_xor(a3, 16);
    a4 += __shfl_xor(a4, 16); a5 += __shfl_xor(a5, 16);
    a6 += __shfl_xor(a6, 16); a7 += __shfl_xor(a7, 16);
    a0 += __shfl_xor(a0, 32); a1 += __shfl_xor(a1, 32);
    a2 += __shfl_xor(a2, 32); a3 += __shfl_xor(a3, 32);
    a4 += __shfl_xor(a4, 32); a5 += __shfl_xor(a5, 32);
    a6 += __shfl_xor(a6, 32); a7 += __shfl_xor(a7, 32);
    if (lane < 8) {
        const float nn = inorm[node];
        const f4 b0 = *(const f4*)(bias + col);
        const f4 b1 = *(const f4*)(bias + col + 4);
        f4 r0 = {a0 * nn + b0.x, a1 * nn + b0.y, a2 * nn + b0.z, a3 * nn + b0.w};
        f4 r1 = {a4 * nn + b1.x, a5 * nn + b1.y, a6 * nn + b1.z, a7 * nn + b1.w};
        *(f4*)(out + (size_t)node * 64 + col) = r0;
        *(f4*)(out + (size_t)node * 64 + col + 4) = r1;
    }
}

// MFMA GEMM: C[N x COLS] = A[N x 128] @ W[128 x COLS] (+bias,+relu,+row-norm)
template <int COLS, bool RELU, bool BIAS, bool NORM>
__global__ void __launch_bounds__(256)
k_mgemm(const u16* __restrict__ A, const u16* __restrict__ Wt,
        const float* __restrict__ bias, const float* __restrict__ norm,
        u16* __restrict__ C, int N) {
    __shared__ u16 Wl[COLS][136];
    const int t = threadIdx.x;
    const int lane = t & 63;
    const int wave = t >> 6;
    #pragma unroll
    for (int i = 0; i < COLS / 16; ++i) {
        const int elem = (i * 256 + t) * 8;
        const int r = elem >> 7, c0 = elem & 127;
        *(short8*)&Wl[r][c0] = *(const short8*)(Wt + elem);
    }
    const int row0 = blockIdx.x * 64 + wave * 16;
    const int arow = min(row0 + (lane & 15), N - 1);
    const int koff = (lane >> 4) * 8;
    short8 a[4];
    #pragma unroll
    for (int kk = 0; kk < 4; ++kk)
        a[kk] = *(const short8*)(A + (size_t)arow * 128 + kk * 32 + koff);
    __syncthreads();

    f4 acc[COLS / 16];
    #pragma unroll
    for (int ct = 0; ct < COLS / 16; ++ct) acc[ct] = (f4){0.f, 0.f, 0.f, 0.f};

    #pragma unroll
    for (int ct = 0; ct < COLS / 16; ++ct) {
        #pragma unroll
        for (int kk = 0; kk < 4; ++kk) {
            const short8 b = *(const short8*)&Wl[ct * 16 + (lane & 15)][kk * 32 + koff];
            acc[ct] = __builtin_amdgcn_mfma_f32_16x16x32_bf16(a[kk], b, acc[ct], 0, 0, 0);
        }
    }

    float nr[4];
    #pragma unroll
    for (int r = 0; r < 4; ++r) {
        const int gr = row0 + (lane >> 4) * 4 + r;
        nr[r] = (NORM && gr < N) ? norm[gr] : 1.f;
    }

    #pragma unroll
    for (int ct = 0; ct < COLS / 16; ++ct) {
        const int c = ct * 16 + (lane & 15);
        const float bb = BIAS ? bias[c] : 0.f;
        #pragma unroll
        for (int r = 0; r < 4; ++r) {
            const int gr = row0 + (lane >> 4) * 4 + r;
            if (gr < N) {
                float v = acc[ct][r] + bb;
                if (RELU) v = v > 0.f ? v : 0.f;
                if (NORM) v *= nr[r];
                C[(size_t)gr * COLS + c] = bfrn(v);
            }
        }
    }
}

extern "C" void kernel_launch(void* const* d_in, const int* in_sizes, int n_in,
                              void* d_out, int out_size, void* d_ws, size_t ws_size,
                              hipStream_t stream) {
    const float* feat = (const float*)d_in[0];
    const int*   src  = (const int*)d_in[1];
    const int*   dst  = (const int*)d_in[2];
    const float* ew   = (const float*)d_in[3];
    const float* W0   = (const float*)d_in[4];
    const float* b0   = (const float*)d_in[5];
    const float* W1   = (const float*)d_in[6];
    const float* b1   = (const float*)d_in[7];
    const float* W2   = (const float*)d_in[8];
    const float* b2   = (const float*)d_in[9];
    float* out = (float*)d_out;

    const int N = in_sizes[0] / 128;
    const int E = in_sizes[1];
    const int NB = (N + 255) / 256;
    const int B1 = (E + EPB - 1) / EPB;

    uint8_t* wp = (uint8_t*)d_ws;
    auto alloc = [&](size_t bytes) {
        uint8_t* r = wp;
        wp += (bytes + 511) & ~(size_t)511;
        return r;
    };
    u16*   featb = (u16*)alloc((size_t)N * 128 * 2);  // onorm-scaled feat; layer-1 GEMM out
    u16*   Xb    = (u16*)alloc((size_t)N * 128 * 2);  // aliases prep hists
    u16*   Tb    = (u16*)alloc((size_t)N * 128 * 2);  // agg output (ping)
    u8*    scr   = (u8*)alloc((size_t)E * 10 + 65536); // tsw+tsrc; later Gb
    int2*  csr   = (int2*)alloc((size_t)E * 8);
    int*   row   = (int*)alloc((size_t)(N + 1) * 4);
    float* onorm = (float*)alloc((size_t)N * 4);
    float* inorm = (float*)alloc((size_t)N * 4);
    u16*   Wt0   = (u16*)alloc(128 * 128 * 2);
    u16*   Wt1   = (u16*)alloc(128 * 128 * 2);
    u16*   Wt2   = (u16*)alloc(128 * 64 * 2);

    // prep-phase aliases inside Xb (dead before Xb first written by layer-0 GEMM)
    uint8_t* xp = (uint8_t*)Xb;
    auto xalloc = [&](size_t bytes) {
        uint8_t* r = xp;
        xp += (bytes + 511) & ~(size_t)511;
        return r;
    };
    int* bh_d   = (int*)xalloc((size_t)B1 * NB * 4);
    int* bh_s   = (int*)xalloc((size_t)B1 * NB * 4);
    int* cb_d   = (int*)xalloc((size_t)NB * 4);
    int* cb_s   = (int*)xalloc((size_t)NB * 4);
    int* bktb_d = (int*)xalloc((size_t)NB * 4);
    int* bktb_s = (int*)xalloc((size_t)NB * 4);

    // prep tables + layer-2 G inside scr
    uint8_t* yp = scr;
    auto yalloc = [&](size_t bytes) {
        uint8_t* r = yp;
        yp += (bytes + 511) & ~(size_t)511;
        return r;
    };
    int2* tsw  = (int2*)yalloc((size_t)E * 8);
    u8*   tsrc = (u8*)yalloc((size_t)E);
    u16*  Gb   = (u16*)scr;   // written by layer-2 GEMM after prep complete

    // ---- CSR build (LDS atomics only) + onorm-folded conversions ----
    k_prep0<<<B1 + 160, 256, 0, stream>>>(src, dst, bh_s, bh_d,
                                          W0, W1, W2, Wt0, Wt1, Wt2, NB, B1, E);
    k_p2<<<dim3((NB + 15) / 16, 2), 512, 0, stream>>>(bh_d, bh_s, cb_d, cb_s, NB, B1);
    k_p2b<<<1, 512, 0, stream>>>(cb_d, cb_s, bktb_d, bktb_s, row, NB, N, E);
    k_p3<<<B1, 256, 0, stream>>>(src, dst, ew, bh_s, bh_d, bktb_s, bktb_d,
                                 tsw, tsrc, NB, E);
    k_p4<<<dim3(NB, 2), 256, 0, stream>>>(tsrc, tsw, bktb_s, cb_s, bktb_d, cb_d,
                                          feat, featb, onorm, row, inorm, csr,
                                          NB, N);

    // ---- 3 GraphConv layers ----
    const int ab = (N + 3) / 4;
    const int gb = (N + 63) / 64;

    // layer 0: agg(featb) -> Tb ; Xb = onorm .* relu(Tb@W0 + b0)
    k_agg128b<<<ab, 256, 0, stream>>>(featb, row, csr, inorm, Tb, N);
    k_mgemm<128, true, true, true><<<gb, 256, 0, stream>>>(Tb, Wt0, b0, onorm, Xb, N);
    // layer 1: agg(Xb) -> Tb ; featb = onorm .* relu(Tb@W1 + b1)
    k_agg128b<<<ab, 256, 0, stream>>>(Xb, row, csr, inorm, Tb, N);
    k_mgemm<128, true, true, true><<<gb, 256, 0, stream>>>(Tb, Wt1, b1, onorm, featb, N);
    // layer 2: Gb = featb@W2 ; out = inorm .* agg(Gb) + b2
    k_mgemm<64, false, false, false><<<gb, 256, 0, stream>>>(featb, Wt2, nullptr, nullptr, Gb, N);
    k_agg64b<<<ab, 256, 0, stream>>>(Gb, row, csr, inorm, b2, out, N);
}

// Round 11
// 297.668 us; speedup vs baseline: 1.1858x; 1.0186x over previous
//
#include <hip/hip_runtime.h>
#include <cstddef>
#include <cstdint>

typedef float f4 __attribute__((ext_vector_type(4)));
typedef unsigned long long u64;
typedef unsigned short u16;
typedef unsigned char u8;
typedef unsigned short u16x8 __attribute__((ext_vector_type(8)));
typedef short short8 __attribute__((ext_vector_type(8)));

__device__ __forceinline__ u64 ldnt8(const void* p) {
    return __builtin_nontemporal_load((const u64*)(p));
}
// bf16 round-to-nearest-even
__device__ __forceinline__ u16 bfrn(float f) {
    unsigned u = __float_as_uint(f);
    return (u16)((u + 0x7FFFu + ((u >> 16) & 1u)) >> 16);
}
__device__ __forceinline__ float bl(unsigned w) { return __uint_as_float(w << 16); }
__device__ __forceinline__ float bh(unsigned w) { return __uint_as_float(w & 0xFFFF0000u); }

// ---------------------------------------------------------------------------
// GraphConv x3 (DGL norm='both', per-edge weight)
// onorm folded into the stored operand: featb = bf16(onorm .* feat);
// layer-0/1 GEMM epilogue rescales by onorm[row] => csr coef = ew exactly.
// CSR build: two-level counting sort (LDS atomics only), EPB=8192 so each
// (block,bucket) scatter run is ~21 entries (~168B) -> less 64B-line waste.
// Layers: split agg (bf16 gather, fp32 acc) + MFMA GEMM (proven).
// ---------------------------------------------------------------------------

#define EPB 8192

// fused: blocks [0,B1) = coarse histograms; [B1,B1+160) = W cvt
__global__ void __launch_bounds__(256)
k_prep0(const int* __restrict__ src, const int* __restrict__ dst,
        int* __restrict__ bh_s, int* __restrict__ bh_d,
        const float* __restrict__ W0, const float* __restrict__ W1,
        const float* __restrict__ W2, u16* __restrict__ Wt0,
        u16* __restrict__ Wt1, u16* __restrict__ Wt2,
        int NB, int B1, int E) {
    const int bid = blockIdx.x, t = threadIdx.x;
    if (bid < B1) {
        __shared__ int hs[512], hd[512];
        for (int i = t; i < 512; i += 256) { hs[i] = 0; hd[i] = 0; }
        __syncthreads();
        const int e0 = bid * EPB;
        #pragma unroll
        for (int j = 0; j < 8; ++j) {
            const int e = e0 + j * 1024 + t * 4;
            if (e + 4 <= E) {
                const int4 d = *(const int4*)&dst[e];
                const int4 s = *(const int4*)&src[e];
                atomicAdd(&hd[d.x >> 8], 1);
                atomicAdd(&hd[d.y >> 8], 1);
                atomicAdd(&hd[d.z >> 8], 1);
                atomicAdd(&hd[d.w >> 8], 1);
                atomicAdd(&hs[s.x >> 8], 1);
                atomicAdd(&hs[s.y >> 8], 1);
                atomicAdd(&hs[s.z >> 8], 1);
                atomicAdd(&hs[s.w >> 8], 1);
            } else {
                for (int k = e; k < E && k < e + 4; ++k) {
                    atomicAdd(&hd[dst[k] >> 8], 1);
                    atomicAdd(&hs[src[k] >> 8], 1);
                }
            }
        }
        __syncthreads();
        for (int i = t; i < NB; i += 256) {
            bh_d[bid * NB + i] = hd[i];
            bh_s[bid * NB + i] = hs[i];
        }
    } else {
        const int i = (bid - B1) * 256 + t;
        if (i < 16384) {
            const int k = i >> 7, c = i & 127;
            Wt0[c * 128 + k] = bfrn(W0[i]);
        } else if (i < 32768) {
            const int j = i - 16384, k = j >> 7, c = j & 127;
            Wt1[c * 128 + k] = bfrn(W1[j]);
        } else if (i < 40960) {
            const int j = i - 32768, k = j >> 6, c = j & 63;
            Wt2[c * 128 + k] = bfrn(W2[j]);
        }
    }
}

// P2: per bucket exclusive scan over blocks; coalesced via 512x16 LDS tile.
__global__ void __launch_bounds__(512)
k_p2(int* __restrict__ bh_d, int* __restrict__ bh_s,
     int* __restrict__ cb_d, int* __restrict__ cb_s, int NB, int B1) {
    __shared__ int tile[512][17];
    __shared__ int tot[16];
    const int t = threadIdx.x, lane = t & 63, wave = t >> 6;
    int* bh = blockIdx.y ? bh_s : bh_d;
    int* cb = blockIdx.y ? cb_s : cb_d;
    const int B0 = blockIdx.x * 16;
    #pragma unroll
    for (int j = 0; j < 16; ++j) {
        const int idx = j * 512 + t;
        const int row = idx >> 4, col = idx & 15;
        int v = 0;
        if (row < B1 && B0 + col < NB) v = bh[row * NB + B0 + col];
        tile[row][col] = v;
    }
    __syncthreads();
    #pragma unroll
    for (int cc = 0; cc < 2; ++cc) {
        const int col = wave * 2 + cc;
        int carry = 0;
        #pragma unroll
        for (int ch = 0; ch < 8; ++ch) {
            const int v = tile[ch * 64 + lane][col];
            int s = v;
            #pragma unroll
            for (int d = 1; d < 64; d <<= 1) {
                const int u = __shfl_up(s, d);
                if (lane >= d) s += u;
            }
            tile[ch * 64 + lane][col] = s - v + carry;
            carry += __shfl(s, 63);
        }
        if (lane == 0) tot[col] = carry;
    }
    __syncthreads();
    #pragma unroll
    for (int j = 0; j < 16; ++j) {
        const int idx = j * 512 + t;
        const int row = idx >> 4, col = idx & 15;
        if (row < B1 && B0 + col < NB) bh[row * NB + B0 + col] = tile[row][col];
    }
    if (t < 16 && B0 + t < NB) cb[B0 + t] = tot[t];
}

__global__ void __launch_bounds__(512)
k_p2b(const int* __restrict__ cb_d, const int* __restrict__ cb_s,
      int* __restrict__ bktb_d, int* __restrict__ bktb_s,
      int* __restrict__ row, int NB, int N, int E) {
    __shared__ int s[512];
    const int t = threadIdx.x;
    int v = (t < NB) ? cb_d[t] : 0;
    s[t] = v;
    __syncthreads();
    for (int off = 1; off < 512; off <<= 1) {
        const int x = (t >= off) ? s[t - off] : 0;
        __syncthreads();
        s[t] += x;
        __syncthreads();
    }
    if (t < NB) bktb_d[t] = s[t] - v;
    __syncthreads();
    v = (t < NB) ? cb_s[t] : 0;
    s[t] = v;
    __syncthreads();
    for (int off = 1; off < 512; off <<= 1) {
        const int x = (t >= off) ? s[t - off] : 0;
        __syncthreads();
        s[t] += x;
        __syncthreads();
    }
    if (t < NB) bktb_s[t] = s[t] - v;
    if (t == 0) row[N] = E;
}

__global__ void __launch_bounds__(256)
k_p3(const int* __restrict__ src, const int* __restrict__ dst,
     const float* __restrict__ ew,
     const int* __restrict__ bh_s, const int* __restrict__ bh_d,
     const int* __restrict__ bktb_s, const int* __restrict__ bktb_d,
     int2* __restrict__ tsw, u8* __restrict__ tsrc, int NB, int E) {
    __shared__ int hs[512], hd[512], base_s[512], base_d[512];
    const int t = threadIdx.x, b = blockIdx.x;
    for (int i = t; i < 512; i += 256) {
        hs[i] = 0; hd[i] = 0;
        if (i < NB) {
            base_d[i] = bktb_d[i] + bh_d[b * NB + i];
            base_s[i] = bktb_s[i] + bh_s[b * NB + i];
        }
    }
    __syncthreads();
    const int e0 = b * EPB;
    #pragma unroll
    for (int j = 0; j < 8; ++j) {
        const int e = e0 + j * 1024 + t * 4;
        if (e + 4 <= E) {
            const int4 d = *(const int4*)&dst[e];
            const int4 s = *(const int4*)&src[e];
            const f4   w = *(const f4*)&ew[e];
            const int dd[4] = {d.x, d.y, d.z, d.w};
            const int ss[4] = {s.x, s.y, s.z, s.w};
            const float ww[4] = {w.x, w.y, w.z, w.w};
            #pragma unroll
            for (int k = 0; k < 4; ++k) {
                const int Bd = dd[k] >> 8;
                const int rd = atomicAdd(&hd[Bd], 1);
                tsw[base_d[Bd] + rd] = make_int2(ss[k] | ((dd[k] & 255) << 24),
                                                 __float_as_int(ww[k]));
                const int Bs = ss[k] >> 8;
                const int rs = atomicAdd(&hs[Bs], 1);
                tsrc[base_s[Bs] + rs] = (u8)(ss[k] & 255);
            }
        } else {
            for (int k = e; k < E && k < e + 4; ++k) {
                const int dv = dst[k], sv = src[k];
                const int Bd = dv >> 8;
                const int rd = atomicAdd(&hd[Bd], 1);
                tsw[base_d[Bd] + rd] = make_int2(sv | ((dv & 255) << 24),
                                                 __float_as_int(ew[k]));
                const int Bs = sv >> 8;
                const int rs = atomicAdd(&hs[Bs], 1);
                tsrc[base_s[Bs] + rs] = (u8)(sv & 255);
            }
        }
    }
}

// P4 fused: y=0 -> outdeg/onorm + feat scale/cvt; y=1 -> fine sort -> csr
__global__ void __launch_bounds__(256)
k_p4(const u8* __restrict__ tsrc, const int2* __restrict__ tsw,
     const int* __restrict__ bktb_s, const int* __restrict__ cb_s,
     const int* __restrict__ bktb_d, const int* __restrict__ cb_d,
     const float* __restrict__ feat, u16* __restrict__ featb,
     float* __restrict__ onorm, int* __restrict__ row,
     float* __restrict__ inorm, int2* __restrict__ csr, int NB, int N) {
    const int B = blockIdx.x, t = threadIdx.x;
    if (blockIdx.y == 0) {
        __shared__ int cnt[256];
        __shared__ float nrm[256];
        cnt[t] = 0;
        __syncthreads();
        const int base = bktb_s[B], cb = cb_s[B];
        for (int i = t; i < cb; i += 256) atomicAdd(&cnt[tsrc[base + i]], 1);
        __syncthreads();
        const int n = (B << 8) + t;
        const int c = cnt[t];
        const float o = rsqrtf((float)(c < 1 ? 1 : c));
        nrm[t] = o;
        if (n < N) onorm[n] = o;
        __syncthreads();
        const int n0 = B << 8;
        for (int idx = t; idx < 256 * 16; idx += 256) {
            const int node = idx >> 4, g = idx & 15;
            const int gn = n0 + node;
            if (gn < N) {
                const float o2 = nrm[node];
                const f4 v0 = *(const f4*)(feat + (size_t)gn * 128 + g * 8);
                const f4 v1 = *(const f4*)(feat + (size_t)gn * 128 + g * 8 + 4);
                u16x8 r = {bfrn(v0.x * o2), bfrn(v0.y * o2),
                           bfrn(v0.z * o2), bfrn(v0.w * o2),
                           bfrn(v1.x * o2), bfrn(v1.y * o2),
                           bfrn(v1.z * o2), bfrn(v1.w * o2)};
                *(u16x8*)(featb + (size_t)gn * 128 + g * 8) = r;
            }
        }
    } else {
        __shared__ int cnt[256], cnt2[256], lrow[256], sc[256];
        cnt[t] = 0; cnt2[t] = 0;
        __syncthreads();
        const int base = bktb_d[B], cb = cb_d[B];
        for (int i = t; i < cb; i += 256)
            atomicAdd(&cnt[((unsigned)tsw[base + i].x) >> 24], 1);
        __syncthreads();
        const int v = cnt[t];
        sc[t] = v;
        __syncthreads();
        for (int off = 1; off < 256; off <<= 1) {
            const int x = (t >= off) ? sc[t - off] : 0;
            __syncthreads();
            sc[t] += x;
            __syncthreads();
        }
        const int excl = sc[t] - v;
        lrow[t] = excl;
        const int n = (B << 8) + t;
        if (n < N) {
            row[n] = base + excl;
            inorm[n] = rsqrtf((float)(v < 1 ? 1 : v));
        }
        __syncthreads();
        for (int i = t; i < cb; i += 256) {
            const int2 sw = tsw[base + i];
            const int d = ((unsigned)sw.x) >> 24;
            const int r = atomicAdd(&cnt2[d], 1);
            csr[base + lrow[d] + r] = make_int2(sw.x & 0xFFFFFF, sw.y);
        }
    }
}

// one wave per node, width 128 bf16: quarter-wave per edge, 16 edges/iter
__global__ void __launch_bounds__(256)
k_agg128b(const u16* __restrict__ h, const int* __restrict__ row,
          const int2* __restrict__ csr, const float* __restrict__ inorm,
          u16* __restrict__ out, int N) {
    const int node = (int)((blockIdx.x * blockDim.x + threadIdx.x) >> 6);
    if (node >= N) return;
    const int lane = threadIdx.x & 63;
    const int q = lane >> 4;
    const int col = (lane & 15) * 8;
    int p = row[node];
    const int e = row[node + 1];
    float a0 = 0, a1 = 0, a2 = 0, a3 = 0, a4 = 0, a5 = 0, a6 = 0, a7 = 0;
    for (; p + 16 <= e; p += 16) {
        const u64 c0 = ldnt8(&csr[p + q]);
        const u64 c1 = ldnt8(&csr[p + 4 + q]);
        const u64 c2 = ldnt8(&csr[p + 8 + q]);
        const u64 c3 = ldnt8(&csr[p + 12 + q]);
        const uint4 w0 = *(const uint4*)(h + (size_t)(int)c0 * 128 + col);
        const uint4 w1 = *(const uint4*)(h + (size_t)(int)c1 * 128 + col);
        const uint4 w2 = *(const uint4*)(h + (size_t)(int)c2 * 128 + col);
        const uint4 w3 = *(const uint4*)(h + (size_t)(int)c3 * 128 + col);
        const float f0 = __int_as_float((int)(c0 >> 32));
        const float f1 = __int_as_float((int)(c1 >> 32));
        const float f2 = __int_as_float((int)(c2 >> 32));
        const float f3 = __int_as_float((int)(c3 >> 32));
        a0 = fmaf(f0, bl(w0.x), a0); a1 = fmaf(f0, bh(w0.x), a1);
        a2 = fmaf(f0, bl(w0.y), a2); a3 = fmaf(f0, bh(w0.y), a3);
        a4 = fmaf(f0, bl(w0.z), a4); a5 = fmaf(f0, bh(w0.z), a5);
        a6 = fmaf(f0, bl(w0.w), a6); a7 = fmaf(f0, bh(w0.w), a7);
        a0 = fmaf(f1, bl(w1.x), a0); a1 = fmaf(f1, bh(w1.x), a1);
        a2 = fmaf(f1, bl(w1.y), a2); a3 = fmaf(f1, bh(w1.y), a3);
        a4 = fmaf(f1, bl(w1.z), a4); a5 = fmaf(f1, bh(w1.z), a5);
        a6 = fmaf(f1, bl(w1.w), a6); a7 = fmaf(f1, bh(w1.w), a7);
        a0 = fmaf(f2, bl(w2.x), a0); a1 = fmaf(f2, bh(w2.x), a1);
        a2 = fmaf(f2, bl(w2.y), a2); a3 = fmaf(f2, bh(w2.y), a3);
        a4 = fmaf(f2, bl(w2.z), a4); a5 = fmaf(f2, bh(w2.z), a5);
        a6 = fmaf(f2, bl(w2.w), a6); a7 = fmaf(f2, bh(w2.w), a7);
        a0 = fmaf(f3, bl(w3.x), a0); a1 = fmaf(f3, bh(w3.x), a1);
        a2 = fmaf(f3, bl(w3.y), a2); a3 = fmaf(f3, bh(w3.y), a3);
        a4 = fmaf(f3, bl(w3.z), a4); a5 = fmaf(f3, bh(w3.z), a5);
        a6 = fmaf(f3, bl(w3.w), a6); a7 = fmaf(f3, bh(w3.w), a7);
    }
    for (; p + 8 <= e; p += 8) {
        const u64 c0 = ldnt8(&csr[p + q]);
        const u64 c1 = ldnt8(&csr[p + 4 + q]);
        const uint4 w0 = *(const uint4*)(h + (size_t)(int)c0 * 128 + col);
        const uint4 w1 = *(const uint4*)(h + (size_t)(int)c1 * 128 + col);
        const float f0 = __int_as_float((int)(c0 >> 32));
        const float f1 = __int_as_float((int)(c1 >> 32));
        a0 = fmaf(f0, bl(w0.x), a0); a1 = fmaf(f0, bh(w0.x), a1);
        a2 = fmaf(f0, bl(w0.y), a2); a3 = fmaf(f0, bh(w0.y), a3);
        a4 = fmaf(f0, bl(w0.z), a4); a5 = fmaf(f0, bh(w0.z), a5);
        a6 = fmaf(f0, bl(w0.w), a6); a7 = fmaf(f0, bh(w0.w), a7);
        a0 = fmaf(f1, bl(w1.x), a0); a1 = fmaf(f1, bh(w1.x), a1);
        a2 = fmaf(f1, bl(w1.y), a2); a3 = fmaf(f1, bh(w1.y), a3);
        a4 = fmaf(f1, bl(w1.z), a4); a5 = fmaf(f1, bh(w1.z), a5);
        a6 = fmaf(f1, bl(w1.w), a6); a7 = fmaf(f1, bh(w1.w), a7);
    }
    {
        const int i0 = p + q, i1 = p + 4 + q;
        if (i0 < e) {
            const u64 c = ldnt8(&csr[i0]);
            const uint4 w = *(const uint4*)(h + (size_t)(int)c * 128 + col);
            const float f = __int_as_float((int)(c >> 32));
            a0 = fmaf(f, bl(w.x), a0); a1 = fmaf(f, bh(w.x), a1);
            a2 = fmaf(f, bl(w.y), a2); a3 = fmaf(f, bh(w.y), a3);
            a4 = fmaf(f, bl(w.z), a4); a5 = fmaf(f, bh(w.z), a5);
            a6 = fmaf(f, bl(w.w), a6); a7 = fmaf(f, bh(w.w), a7);
        }
        if (i1 < e) {
            const u64 c = ldnt8(&csr[i1]);
            const uint4 w = *(const uint4*)(h + (size_t)(int)c * 128 + col);
            const float f = __int_as_float((int)(c >> 32));
            a0 = fmaf(f, bl(w.x), a0); a1 = fmaf(f, bh(w.x), a1);
            a2 = fmaf(f, bl(w.y), a2); a3 = fmaf(f, bh(w.y), a3);
            a4 = fmaf(f, bl(w.z), a4); a5 = fmaf(f, bh(w.z), a5);
            a6 = fmaf(f, bl(w.w), a6); a7 = fmaf(f, bh(w.w), a7);
        }
    }
    a0 += __shfl_xor(a0, 16); a1 += __shfl_xor(a1, 16);
    a2 += __shfl_xor(a2, 16); a3 += __shfl_xor(a3, 16);
    a4 += __shfl_xor(a4, 16); a5 += __shfl_xor(a5, 16);
    a6 += __shfl_xor(a6, 16); a7 += __shfl_xor(a7, 16);
    a0 += __shfl_xor(a0, 32); a1 += __shfl_xor(a1, 32);
    a2 += __shfl_xor(a2, 32); a3 += __shfl_xor(a3, 32);
    a4 += __shfl_xor(a4, 32); a5 += __shfl_xor(a5, 32);
    a6 += __shfl_xor(a6, 32); a7 += __shfl_xor(a7, 32);
    if (lane < 16) {
        const float nn = inorm[node];
        u16x8 r = {bfrn(a0 * nn), bfrn(a1 * nn), bfrn(a2 * nn), bfrn(a3 * nn),
                   bfrn(a4 * nn), bfrn(a5 * nn), bfrn(a6 * nn), bfrn(a7 * nn)};
        *(u16x8*)(out + (size_t)node * 128 + col) = r;
    }
}

// one wave per node, width 64 bf16: eighth-wave per edge; fused bias; fp32 out
__global__ void __launch_bounds__(256)
k_agg64b(const u16* __restrict__ h, const int* __restrict__ row,
         const int2* __restrict__ csr, const float* __restrict__ inorm,
         const float* __restrict__ bias, float* __restrict__ out, int N) {
    const int node = (int)((blockIdx.x * blockDim.x + threadIdx.x) >> 6);
    if (node >= N) return;
    const int lane = threadIdx.x & 63;
    const int oc = lane >> 3;
    const int col = (lane & 7) * 8;
    int p = row[node];
    const int e = row[node + 1];
    float a0 = 0, a1 = 0, a2 = 0, a3 = 0, a4 = 0, a5 = 0, a6 = 0, a7 = 0;
    for (; p + 16 <= e; p += 16) {
        const u64 c0 = ldnt8(&csr[p + oc]);
        const u64 c1 = ldnt8(&csr[p + 8 + oc]);
        const uint4 w0 = *(const uint4*)(h + (size_t)(int)c0 * 64 + col);
        const uint4 w1 = *(const uint4*)(h + (size_t)(int)c1 * 64 + col);
        const float f0 = __int_as_float((int)(c0 >> 32));
        const float f1 = __int_as_float((int)(c1 >> 32));
        a0 = fmaf(f0, bl(w0.x), a0); a1 = fmaf(f0, bh(w0.x), a1);
        a2 = fmaf(f0, bl(w0.y), a2); a3 = fmaf(f0, bh(w0.y), a3);
        a4 = fmaf(f0, bl(w0.z), a4); a5 = fmaf(f0, bh(w0.z), a5);
        a6 = fmaf(f0, bl(w0.w), a6); a7 = fmaf(f0, bh(w0.w), a7);
        a0 = fmaf(f1, bl(w1.x), a0); a1 = fmaf(f1, bh(w1.x), a1);
        a2 = fmaf(f1, bl(w1.y), a2); a3 = fmaf(f1, bh(w1.y), a3);
        a4 = fmaf(f1, bl(w1.z), a4); a5 = fmaf(f1, bh(w1.z), a5);
        a6 = fmaf(f1, bl(w1.w), a6); a7 = fmaf(f1, bh(w1.w), a7);
    }
    {
        const int i0 = p + oc, i1 = p + 8 + oc;
        if (i0 < e) {
            const u64 c = ldnt8(&csr[i0]);
            const uint4 w = *(const uint4*)(h + (size_t)(int)c * 64 + col);
            const float f = __int_as_float((int)(c >> 32));
            a0 = fmaf(f, bl(w.x), a0); a1 = fmaf(f, bh(w.x), a1);
            a2 = fmaf(f, bl(w.y), a2); a3 = fmaf(f, bh(w.y), a3);
            a4 = fmaf(f, bl(w.z), a4); a5 = fmaf(f, bh(w.z), a5);
            a6 = fmaf(f, bl(w.w), a6); a7 = fmaf(f, bh(w.w), a7);
        }
        if (i1 < e) {
            const u64 c = ldnt8(&csr[i1]);
            const uint4 w = *(const uint4*)(h + (size_t)(int)c * 64 + col);
            const float f = __int_as_float((int)(c >> 32));
            a0 = fmaf(f, bl(w.x), a0); a1 = fmaf(f, bh(w.x), a1);
            a2 = fmaf(f, bl(w.y), a2); a3 = fmaf(f, bh(w.y), a3);
            a4 = fmaf(f, bl(w.z), a4); a5 = fmaf(f, bh(w.z), a5);
            a6 = fmaf(f, bl(w.w), a6); a7 = fmaf(f, bh(w.w), a7);
        }
    }
    a0 += __shfl_xor(a0, 8);  a1 += __shfl_xor(a1, 8);
    a2 += __shfl_xor(a2, 8);  a3 += __shfl_xor(a3, 8);
    a4 += __shfl_xor(a4, 8);  a5 += __shfl_xor(a5, 8);
    a6 += __shfl_xor(a6, 8);  a7 += __shfl_xor(a7, 8);
    a0 += __shfl_xor(a0, 16); a1 += __shfl_xor(a1, 16);
    a2 += __shfl_xor(a2, 16); a3 += __shfl_xor(a3, 16);
    a4 += __shfl_xor(a4, 16); a5 += __shfl_xor(a5, 16);
    a6 += __shfl_xor(a6, 16); a7 += __shfl_xor(a7, 16);
    a0 += __shfl_xor(a0, 32); a1 += __shfl_xor(a1, 32);
    a2 += __shfl_xor(a2, 32); a3 += __shfl_xor(a3, 32);
    a4 += __shfl_xor(a4, 32); a5 += __shfl_xor(a5, 32);
    a6 += __shfl_xor(a6, 32); a7 += __shfl_xor(a7, 32);
    if (lane < 8) {
        const float nn = inorm[node];
        const f4 b0 = *(const f4*)(bias + col);
        const f4 b1 = *(const f4*)(bias + col + 4);
        f4 r0 = {a0 * nn + b0.x, a1 * nn + b0.y, a2 * nn + b0.z, a3 * nn + b0.w};
        f4 r1 = {a4 * nn + b1.x, a5 * nn + b1.y, a6 * nn + b1.z, a7 * nn + b1.w};
        *(f4*)(out + (size_t)node * 64 + col) = r0;
        *(f4*)(out + (size_t)node * 64 + col + 4) = r1;
    }
}

// MFMA GEMM: C[N x COLS] = A[N x 128] @ W[128 x COLS] (+bias,+relu,+row-norm)
template <int COLS, bool RELU, bool BIAS, bool NORM>
__global__ void __launch_bounds__(256)
k_mgemm(const u16* __restrict__ A, const u16* __restrict__ Wt,
        const float* __restrict__ bias, const float* __restrict__ norm,
        u16* __restrict__ C, int N) {
    __shared__ u16 Wl[COLS][136];
    const int t = threadIdx.x;
    const int lane = t & 63;
    const int wave = t >> 6;
    #pragma unroll
    for (int i = 0; i < COLS / 16; ++i) {
        const int elem = (i * 256 + t) * 8;
        const int r = elem >> 7, c0 = elem & 127;
        *(short8*)&Wl[r][c0] = *(const short8*)(Wt + elem);
    }
    const int row0 = blockIdx.x * 64 + wave * 16;
    const int arow = min(row0 + (lane & 15), N - 1);
    const int koff = (lane >> 4) * 8;
    short8 a[4];
    #pragma unroll
    for (int kk = 0; kk < 4; ++kk)
        a[kk] = *(const short8*)(A + (size_t)arow * 128 + kk * 32 + koff);
    __syncthreads();

    f4 acc[COLS / 16];
    #pragma unroll
    for (int ct = 0; ct < COLS / 16; ++ct) acc[ct] = (f4){0.f, 0.f, 0.f, 0.f};

    #pragma unroll
    for (int ct = 0; ct < COLS / 16; ++ct) {
        #pragma unroll
        for (int kk = 0; kk < 4; ++kk) {
            const short8 b = *(const short8*)&Wl[ct * 16 + (lane & 15)][kk * 32 + koff];
            acc[ct] = __builtin_amdgcn_mfma_f32_16x16x32_bf16(a[kk], b, acc[ct], 0, 0, 0);
        }
    }

    float nr[4];
    #pragma unroll
    for (int r = 0; r < 4; ++r) {
        const int gr = row0 + (lane >> 4) * 4 + r;
        nr[r] = (NORM && gr < N) ? norm[gr] : 1.f;
    }

    #pragma unroll
    for (int ct = 0; ct < COLS / 16; ++ct) {
        const int c = ct * 16 + (lane & 15);
        const float bb = BIAS ? bias[c] : 0.f;
        #pragma unroll
        for (int r = 0; r < 4; ++r) {
            const int gr = row0 + (lane >> 4) * 4 + r;
            if (gr < N) {
                float v = acc[ct][r] + bb;
                if (RELU) v = v > 0.f ? v : 0.f;
                if (NORM) v *= nr[r];
                C[(size_t)gr * COLS + c] = bfrn(v);
            }
        }
    }
}

extern "C" void kernel_launch(void* const* d_in, const int* in_sizes, int n_in,
                              void* d_out, int out_size, void* d_ws, size_t ws_size,
                              hipStream_t stream) {
    const float* feat = (const float*)d_in[0];
    const int*   src  = (const int*)d_in[1];
    const int*   dst  = (const int*)d_in[2];
    const float* ew   = (const float*)d_in[3];
    const float* W0   = (const float*)d_in[4];
    const float* b0   = (const float*)d_in[5];
    const float* W1   = (const float*)d_in[6];
    const float* b1   = (const float*)d_in[7];
    const float* W2   = (const float*)d_in[8];
    const float* b2   = (const float*)d_in[9];
    float* out = (float*)d_out;

    const int N = in_sizes[0] / 128;
    const int E = in_sizes[1];
    const int NB = (N + 255) / 256;
    const int B1 = (E + EPB - 1) / EPB;

    uint8_t* wp = (uint8_t*)d_ws;
    auto alloc = [&](size_t bytes) {
        uint8_t* r = wp;
        wp += (bytes + 511) & ~(size_t)511;
        return r;
    };
    u16*   featb = (u16*)alloc((size_t)N * 128 * 2);  // onorm-scaled feat; layer-1 GEMM out
    u16*   Xb    = (u16*)alloc((size_t)N * 128 * 2);  // aliases prep hists
    u16*   Tb    = (u16*)alloc((size_t)N * 128 * 2);  // agg output (ping)
    u8*    scr   = (u8*)alloc((size_t)E * 10 + 65536); // tsw+tsrc; later Gb
    int2*  csr   = (int2*)alloc((size_t)E * 8);
    int*   row   = (int*)alloc((size_t)(N + 1) * 4);
    float* onorm = (float*)alloc((size_t)N * 4);
    float* inorm = (float*)alloc((size_t)N * 4);
    u16*   Wt0   = (u16*)alloc(128 * 128 * 2);
    u16*   Wt1   = (u16*)alloc(128 * 128 * 2);
    u16*   Wt2   = (u16*)alloc(128 * 64 * 2);

    // prep-phase aliases inside Xb (dead before Xb first written by layer-0 GEMM)
    uint8_t* xp = (uint8_t*)Xb;
    auto xalloc = [&](size_t bytes) {
        uint8_t* r = xp;
        xp += (bytes + 511) & ~(size_t)511;
        return r;
    };
    int* bh_d   = (int*)xalloc((size_t)B1 * NB * 4);
    int* bh_s   = (int*)xalloc((size_t)B1 * NB * 4);
    int* cb_d   = (int*)xalloc((size_t)NB * 4);
    int* cb_s   = (int*)xalloc((size_t)NB * 4);
    int* bktb_d = (int*)xalloc((size_t)NB * 4);
    int* bktb_s = (int*)xalloc((size_t)NB * 4);

    // prep tables + layer-2 G inside scr
    uint8_t* yp = scr;
    auto yalloc = [&](size_t bytes) {
        uint8_t* r = yp;
        yp += (bytes + 511) & ~(size_t)511;
        return r;
    };
    int2* tsw  = (int2*)yalloc((size_t)E * 8);
    u8*   tsrc = (u8*)yalloc((size_t)E);
    u16*  Gb   = (u16*)scr;   // written by layer-2 GEMM after prep complete

    // ---- CSR build (LDS atomics only) + onorm-folded conversions ----
    k_prep0<<<B1 + 160, 256, 0, stream>>>(src, dst, bh_s, bh_d,
                                          W0, W1, W2, Wt0, Wt1, Wt2, NB, B1, E);
    k_p2<<<dim3((NB + 15) / 16, 2), 512, 0, stream>>>(bh_d, bh_s, cb_d, cb_s, NB, B1);
    k_p2b<<<1, 512, 0, stream>>>(cb_d, cb_s, bktb_d, bktb_s, row, NB, N, E);
    k_p3<<<B1, 256, 0, stream>>>(src, dst, ew, bh_s, bh_d, bktb_s, bktb_d,
                                 tsw, tsrc, NB, E);
    k_p4<<<dim3(NB, 2), 256, 0, stream>>>(tsrc, tsw, bktb_s, cb_s, bktb_d, cb_d,
                                          feat, featb, onorm, row, inorm, csr,
                                          NB, N);

    // ---- 3 GraphConv layers ----
    const int ab = (N + 3) / 4;
    const int gb = (N + 63) / 64;

    // layer 0: agg(featb) -> Tb ; Xb = onorm .* relu(Tb@W0 + b0)
    k_agg128b<<<ab, 256, 0, stream>>>(featb, row, csr, inorm, Tb, N);
    k_mgemm<128, true, true, true><<<gb, 256, 0, stream>>>(Tb, Wt0, b0, onorm, Xb, N);
    // layer 1: agg(Xb) -> Tb ; featb = onorm .* relu(Tb@W1 + b1)
    k_agg128b<<<ab, 256, 0, stream>>>(Xb, row, csr, inorm, Tb, N);
    k_mgemm<128, true, true, true><<<gb, 256, 0, stream>>>(Tb, Wt1, b1, onorm, featb, N);
    // layer 2: Gb = featb@W2 ; out = inorm .* agg(Gb) + b2
    k_mgemm<64, false, false, false><<<gb, 256, 0, stream>>>(featb, Wt2, nullptr, nullptr, Gb, N);
    k_agg64b<<<ab, 256, 0, stream>>>(Gb, row, csr, inorm, b2, out, N);
}